// Round 16
// baseline (515.108 us; speedup 1.0000x reference)
//
#include <hip/hip_runtime.h>
#include <hip/hip_bf16.h>
#include <math.h>

#define D_ 128
#define INV_SQRT_D 0.08838834764831845f
#define SCAN_CH 16
#define SCAN_TILE (256 * SCAN_CH)

typedef __bf16 bf16x8 __attribute__((ext_vector_type(8)));
typedef float f32x4 __attribute__((ext_vector_type(4)));
typedef int i32x2 __attribute__((ext_vector_type(2)));

struct W4p { const float* p[4]; };

__device__ __forceinline__ void unpack8(bf16x8 v, float* f) {
    const uint32_t* u = (const uint32_t*)&v;
#pragma unroll
    for (int i = 0; i < 4; i++) {
        uint32_t w = u[i];
        f[2 * i]     = __uint_as_float(w << 16);
        f[2 * i + 1] = __uint_as_float(w & 0xffff0000u);
    }
}

__device__ __forceinline__ bf16x8 pack8(const float* f, float s) {
    bf16x8 r;
#pragma unroll
    for (int j = 0; j < 8; j++) r[j] = (__bf16)(f[j] * s);
    return r;
}

__device__ __forceinline__ float bf2f(__bf16 v) {
    return __uint_as_float((uint32_t)(*(unsigned short*)&v) << 16);
}

// ---------------- merged prep: weight/p-table casts + emb casts + edge histogram ----------------
struct PrepArgs {
    W4p w; const float* pV; const float* pK;
    __bf16* outW; __bf16* pVb; __bf16* pKb; int npv; int npk;
    const float* u_emb; const float* i_emb; __bf16* ub; __bf16* ib;
    size_t nue; size_t nie;
    const int* eu; const int* ei; int* cnt_all; int nu; int E;
    int wb_blocks; int eb_blocks;
};
__global__ __launch_bounds__(256) void prep_all(PrepArgs a) {
    int b = blockIdx.x;
    if (b < a.wb_blocks) {
        int idx = b * 256 + threadIdx.x;
        if (idx < 4 * 16384) {
            a.outW[idx] = (__bf16)a.w.p[idx >> 14][idx & 16383];
        } else if (idx - 4 * 16384 < a.npv) {
            int j = idx - 4 * 16384;
            a.pVb[j] = (__bf16)a.pV[j];
        } else if (idx - 4 * 16384 - a.npv < a.npk) {
            int j = idx - 4 * 16384 - a.npv;
            a.pKb[j] = (__bf16)a.pK[j];
        }
    } else if (b < a.wb_blocks + a.eb_blocks) {
        size_t idx4 = ((size_t)(b - a.wb_blocks) * 256 + threadIdx.x) * 4;
        if (idx4 < a.nue) {
            float4 v = *(const float4*)(a.u_emb + idx4);
            a.ub[idx4] = (__bf16)v.x; a.ub[idx4+1] = (__bf16)v.y; a.ub[idx4+2] = (__bf16)v.z; a.ub[idx4+3] = (__bf16)v.w;
        } else if (idx4 < a.nue + a.nie) {
            size_t j = idx4 - a.nue;
            float4 v = *(const float4*)(a.i_emb + j);
            a.ib[j] = (__bf16)v.x; a.ib[j+1] = (__bf16)v.y; a.ib[j+2] = (__bf16)v.z; a.ib[j+3] = (__bf16)v.w;
        }
    } else {
        int e = (b - a.wb_blocks - a.eb_blocks) * 256 + threadIdx.x;
        if (e < a.E) {
            atomicAdd(&a.cnt_all[a.eu[e]], 1);
            atomicAdd(&a.cnt_all[a.nu + a.ei[e]], 1);
        }
    }
}

// ---------------- combined-matrix prep ----------------
__global__ __launch_bounds__(128) void prep_mats(const float* __restrict__ W1, const float* __restrict__ W2,
                                                 const float* __restrict__ W3, const float* __restrict__ W4,
                                                 const float* __restrict__ pV, const float* __restrict__ pK,
                                                 __bf16* __restrict__ M2t, __bf16* __restrict__ M3t,
                                                 __bf16* __restrict__ M4t,
                                                 __bf16* __restrict__ pVW2, __bf16* __restrict__ pKW1,
                                                 int umax, int imax) {
    __shared__ float sh[256];
    int b = blockIdx.x, t = threadIdx.x;
    if (b < 128) {
        sh[t] = W1[t * 128 + b];
        __syncthreads();
        float m2 = 0.f, m3 = 0.f, m4 = 0.f;
        for (int k = 0; k < 128; k++) {
            float w = sh[k];
            m2 = fmaf(w, W2[k * 128 + t], m2);
            m3 = fmaf(w, W3[k * 128 + t], m3);
            m4 = fmaf(w, W4[k * 128 + t], m4);
        }
        M2t[b * 128 + t] = (__bf16)(m2 * INV_SQRT_D);
        M3t[b * 128 + t] = (__bf16)(m3 * INV_SQRT_D);
        M4t[b * 128 + t] = (__bf16)(m4 * INV_SQRT_D);
    } else {
        int r = b - 128;
        if (r < umax) sh[t] = pV[r * 128 + t];
        if (r < imax) sh[128 + t] = pK[r * 128 + t];
        __syncthreads();
        float q = 0.f, qk = 0.f;
        for (int a = 0; a < 128; a++) {
            if (r < umax) q  = fmaf(sh[a], W2[a * 128 + t], q);
            if (r < imax) qk = fmaf(sh[128 + a], W1[a * 128 + t], qk);
        }
        if (r < umax) pVW2[r * 128 + t] = (__bf16)(q * INV_SQRT_D);
        if (r < imax) pKW1[r * 128 + t] = (__bf16)(qk * INV_SQRT_D);
    }
}

// ---------------- merged: user vectors (y=0) + pvk GEMMs (y=1,2) + scatter (y=3) ----------------
struct PvkA { const __bf16* X; const __bf16* P; __bf16* Y; int rows; int ncols; };
struct VecsPvk {
    const float* u_emb; const float* lit_tab; const int* g_li;
    const float* lut_tab; const int* g_lu;
    const __bf16* M2t; const __bf16* M3t; const __bf16* M4t;
    __bf16* um_t; __bf16* li_t; __bf16* lu_t; int nu;
    PvkA a[2];
    // scatter args
    const int* eu; const int* ei; const int* rui; const int* riu;
    int* pos_all; int* u_list; int E;
};
__global__ __launch_bounds__(256) void vecs_pvk(VecsPvk p) {
    if (blockIdx.y == 3) {
        int e = blockIdx.x * 256 + threadIdx.x;
        if (e < p.E) {
            int u = p.eu[e], it = p.ei[e], r1 = p.rui[e], r2 = p.riu[e];
            int rbits = (r1 << 18) | (r2 << 24);
            int pi = atomicAdd(&p.pos_all[p.nu + it], 1) - p.E;
            int pu = atomicAdd(&p.pos_all[u], 1);
            i32x2 rec;
            rec[0] = it | rbits;
            rec[1] = pi;
            __builtin_nontemporal_store(rec, (i32x2*)(p.u_list + (size_t)pu * 2));
        }
        return;
    }
    int lane = threadIdx.x & 63;
    int wave = threadIdx.x >> 6;
    int row0 = blockIdx.x * 64 + wave * 16;
    int l16 = lane & 15, kh = lane >> 4;
    if (blockIdx.y == 0) {
        int rows = p.nu;
        if (row0 >= rows) return;
        int ar = row0 + l16;
        int arc = ar < rows ? ar : rows - 1;
        const float* rA = p.u_emb + (size_t)arc * D_;
        const float* rB = p.lit_tab + (size_t)p.g_li[arc] * D_;
        const float* rC = p.lut_tab + (size_t)p.g_lu[arc] * D_;

        f32x4 aA[8] = {}, aB[8] = {}, aC[8] = {};
#pragma unroll
        for (int k0 = 0; k0 < D_; k0 += 32) {
            int kk = k0 + kh * 8;
            float4 a0 = *(const float4*)(rA + kk), a1 = *(const float4*)(rA + kk + 4);
            float4 b0 = *(const float4*)(rB + kk), b1 = *(const float4*)(rB + kk + 4);
            float4 c0 = *(const float4*)(rC + kk), c1 = *(const float4*)(rC + kk + 4);
            bf16x8 fA, fB, fC;
            fA[0]=(__bf16)a0.x; fA[1]=(__bf16)a0.y; fA[2]=(__bf16)a0.z; fA[3]=(__bf16)a0.w;
            fA[4]=(__bf16)a1.x; fA[5]=(__bf16)a1.y; fA[6]=(__bf16)a1.z; fA[7]=(__bf16)a1.w;
            fB[0]=(__bf16)b0.x; fB[1]=(__bf16)b0.y; fB[2]=(__bf16)b0.z; fB[3]=(__bf16)b0.w;
            fB[4]=(__bf16)b1.x; fB[5]=(__bf16)b1.y; fB[6]=(__bf16)b1.z; fB[7]=(__bf16)b1.w;
            fC[0]=(__bf16)c0.x; fC[1]=(__bf16)c0.y; fC[2]=(__bf16)c0.z; fC[3]=(__bf16)c0.w;
            fC[4]=(__bf16)c1.x; fC[5]=(__bf16)c1.y; fC[6]=(__bf16)c1.z; fC[7]=(__bf16)c1.w;
#pragma unroll
            for (int cb = 0; cb < 8; cb++) {
                bf16x8 w2 = *(const bf16x8*)(p.M2t + (size_t)(cb * 16 + l16) * D_ + kk);
                aA[cb] = __builtin_amdgcn_mfma_f32_16x16x32_bf16(fA, w2, aA[cb], 0, 0, 0);
                bf16x8 w3 = *(const bf16x8*)(p.M3t + (size_t)(cb * 16 + l16) * D_ + kk);
                aB[cb] = __builtin_amdgcn_mfma_f32_16x16x32_bf16(fB, w3, aB[cb], 0, 0, 0);
                bf16x8 w4 = *(const bf16x8*)(p.M4t + (size_t)(cb * 16 + l16) * D_ + kk);
                aC[cb] = __builtin_amdgcn_mfma_f32_16x16x32_bf16(fC, w4, aC[cb], 0, 0, 0);
            }
        }
#pragma unroll
        for (int cb = 0; cb < 8; cb++) {
#pragma unroll
            for (int j = 0; j < 4; j++) {
                int r = row0 + kh * 4 + j;
                if (r < rows) {
                    p.um_t[(size_t)r * D_ + cb * 16 + l16] = (__bf16)aA[cb][j];
                    p.li_t[(size_t)r * D_ + cb * 16 + l16] = (__bf16)aB[cb][j];
                    p.lu_t[(size_t)r * D_ + cb * 16 + l16] = (__bf16)aC[cb][j];
                }
            }
        }
    } else {
        PvkA q = p.a[blockIdx.y - 1];
        if (row0 >= q.rows) return;
        int ar = row0 + l16;
        int arc = ar < q.rows ? ar : q.rows - 1;
        const __bf16* arow = q.X + (size_t)arc * D_;

        f32x4 acc[4] = {};
#pragma unroll
        for (int k0 = 0; k0 < D_; k0 += 32) {
            int kk = k0 + kh * 8;
            bf16x8 af = *(const bf16x8*)(arow + kk);
#pragma unroll
            for (int cb = 0; cb < 4; cb++) {
                int br = cb * 16 + l16;
                if (br >= q.ncols) br = q.ncols - 1;
                bf16x8 bf = *(const bf16x8*)(q.P + (size_t)br * D_ + kk);
                acc[cb] = __builtin_amdgcn_mfma_f32_16x16x32_bf16(af, bf, acc[cb], 0, 0, 0);
            }
        }
#pragma unroll
        for (int cb = 0; cb < 4; cb++) {
            int col = cb * 16 + l16;
            if (col >= q.ncols) continue;
#pragma unroll
            for (int j = 0; j < 4; j++) {
                int r = row0 + kh * 4 + j;
                if (r < q.rows) q.Y[(size_t)r * q.ncols + col] = (__bf16)acc[cb][j];
            }
        }
    }
}

// ---------------- scans ----------------
__global__ __launch_bounds__(256) void scan_phaseA(const int* __restrict__ cnt, int* __restrict__ part, int n) {
    __shared__ int wsum[4];
    int t = threadIdx.x, lane = t & 63, w = t >> 6;
    int i0 = blockIdx.x * SCAN_TILE + t * SCAN_CH;
    int tot = 0;
#pragma unroll
    for (int j = 0; j < SCAN_CH; j++) tot += (i0 + j < n) ? cnt[i0 + j] : 0;
#pragma unroll
    for (int d = 32; d; d >>= 1) tot += __shfl_xor(tot, d);
    if (lane == 0) wsum[w] = tot;
    __syncthreads();
    if (t == 0) part[blockIdx.x] = wsum[0] + wsum[1] + wsum[2] + wsum[3];
}

__global__ __launch_bounds__(1024) void scan_phaseB(int* __restrict__ part, int nb,
                                                    int* __restrict__ off, int n) {
    __shared__ int wsum[16];
    int t = threadIdx.x, lane = t & 63, w = t >> 6;
    int v = (t < nb) ? part[t] : 0;
    int x = v;
#pragma unroll
    for (int d = 1; d < 64; d <<= 1) {
        int y = __shfl_up(x, d);
        if (lane >= d) x += y;
    }
    if (lane == 63) wsum[w] = x;
    __syncthreads();
    int wbase = 0;
    for (int ww = 0; ww < w; ww++) wbase += wsum[ww];
    if (t < nb) part[t] = wbase + x - v;
    if (t == 1023) off[n] = wbase + x;
}

__global__ __launch_bounds__(256) void scan_phaseC(const int* __restrict__ cnt, const int* __restrict__ part,
                                                   int* __restrict__ off, int* __restrict__ pos, int n) {
    __shared__ int wsum[4];
    int t = threadIdx.x, lane = t & 63, w = t >> 6;
    int i0 = blockIdx.x * SCAN_TILE + t * SCAN_CH;
    int loc[SCAN_CH];
    int tot = 0;
#pragma unroll
    for (int j = 0; j < SCAN_CH; j++) {
        int v = (i0 + j < n) ? cnt[i0 + j] : 0;
        loc[j] = tot; tot += v;
    }
    int x = tot;
#pragma unroll
    for (int d = 1; d < 64; d <<= 1) {
        int y = __shfl_up(x, d);
        if (lane >= d) x += y;
    }
    if (lane == 63) wsum[w] = x;
    __syncthreads();
    int wbase = 0;
    for (int ww = 0; ww < w; ww++) wbase += wsum[ww];
    int excl = part[blockIdx.x] + wbase + x - tot;
#pragma unroll
    for (int j = 0; j < SCAN_CH; j++) {
        if (i0 + j < n) { off[i0 + j] = excl + loc[j]; pos[i0 + j] = excl + loc[j]; }
    }
}

// ---------------- user pass: 4x unroll, gathers issued up-front ----------------
__global__ __launch_bounds__(256) void user_pass(const int* __restrict__ off_all, const int* __restrict__ u_list,
                                                 const __bf16* __restrict__ ib_emb,
                                                 const __bf16* __restrict__ um_t,
                                                 const __bf16* __restrict__ li_t,
                                                 const __bf16* __restrict__ lu_t,
                                                 const __bf16* __restrict__ pKb,
                                                 const __bf16* __restrict__ upv,
                                                 float* __restrict__ mb_rec,
                                                 __bf16* __restrict__ A1n, __bf16* __restrict__ PKn,
                                                 __bf16* __restrict__ A2n, int nu, int umax) {
    int u = blockIdx.x * 4 + (threadIdx.x >> 6);
    if (u >= nu) return;
    int lane = threadIdx.x & 63;
    int g = lane >> 4, l16 = lane & 15;
    int off = off_all[u], n = off_all[u + 1] - off;
    if (n == 0) {
        if (lane < 16) {
            bf16x8 z = {};
            *(bf16x8*)(A1n + (size_t)u * D_ + l16 * 8) = z;
            *(bf16x8*)(PKn + (size_t)u * D_ + l16 * 8) = z;
            *(bf16x8*)(A2n + (size_t)u * D_ + l16 * 8) = z;
        }
        return;
    }
    float um8[8], li8[8], lu8[8];
    unpack8(((const bf16x8*)(um_t + (size_t)u * D_))[l16], um8);
    unpack8(((const bf16x8*)(li_t + (size_t)u * D_))[l16], li8);
    unpack8(((const bf16x8*)(lu_t + (size_t)u * D_))[l16], lu8);
    const __bf16* upv_row = upv + (size_t)u * umax;

    float s1 = 0.f, s2 = 0.f, a1[8] = {}, apk[8] = {}, a2[8] = {};
    for (int i = g; i < n; i += 16) {
        i32x2 rec[4];
        bool ok[4];
#pragma unroll
        for (int s = 0; s < 4; s++) {
            int ii = i + 4 * s;
            ok[s] = ii < n;
            rec[s] = *(const i32x2*)(u_list + (size_t)(off + (ok[s] ? ii : i)) * 2);
        }
        bf16x8 vie[4], vpk[4];
#pragma unroll
        for (int s = 0; s < 4; s++) {
            int it = rec[s][0] & 0x3FFFF;
            int r2 = (rec[s][0] >> 24) & 0x3F;
            vie[s] = ((const bf16x8*)(ib_emb + (size_t)it * D_))[l16];
            vpk[s] = ((const bf16x8*)(pKb + (size_t)r2 * D_))[l16];
        }
#pragma unroll
        for (int s = 0; s < 4; s++) {
            float fie[8];
            unpack8(vie[s], fie);
            float d1 = 0.f, d2 = 0.f, d3 = 0.f;
#pragma unroll
            for (int j = 0; j < 8; j++) {
                d1 = fmaf(um8[j], fie[j], d1);
                d2 = fmaf(li8[j], fie[j], d2);
                d3 = fmaf(lu8[j], fie[j], d3);
            }
#pragma unroll
            for (int d = 1; d < 16; d <<= 1) {
                d1 += __shfl_xor(d1, d);
                d2 += __shfl_xor(d2, d);
                d3 += __shfl_xor(d3, d);
            }
            if (l16 == 0 && ok[s]) {
                f32x4 r;
                r[0] = d1; r[1] = d3;
                r[2] = __int_as_float(u | (rec[s][0] & 0x3FFC0000)); r[3] = 0.f;
                __builtin_nontemporal_store(r, (f32x4*)(mb_rec + (size_t)rec[s][1] * 4));
            }
            int r1 = (rec[s][0] >> 18) & 0x3F;
            float w1 = ok[s] ? __expf(d1 + bf2f(upv_row[r1])) : 0.f;
            float w2 = ok[s] ? __expf(d2) : 0.f;
            s1 += w1; s2 += w2;
            float fpk[8];
            unpack8(vpk[s], fpk);
#pragma unroll
            for (int j = 0; j < 8; j++) {
                a1[j]  = fmaf(w1, fie[j], a1[j]);
                apk[j] = fmaf(w1, fpk[j], apk[j]);
                a2[j]  = fmaf(w2, fie[j], a2[j]);
            }
        }
    }
#pragma unroll
    for (int d = 16; d < 64; d <<= 1) {
        s1 += __shfl_xor(s1, d); s2 += __shfl_xor(s2, d);
#pragma unroll
        for (int j = 0; j < 8; j++) {
            a1[j]  += __shfl_xor(a1[j], d);
            apk[j] += __shfl_xor(apk[j], d);
            a2[j]  += __shfl_xor(a2[j], d);
        }
    }
    if (lane < 16) {
        float inv1 = 1.f / s1, inv2 = 1.f / s2;
        *(bf16x8*)(A1n + (size_t)u * D_ + l16 * 8) = pack8(a1, inv1);
        *(bf16x8*)(PKn + (size_t)u * D_ + l16 * 8) = pack8(apk, inv1);
        *(bf16x8*)(A2n + (size_t)u * D_ + l16 * 8) = pack8(a2, inv2);
    }
}

// ---------------- item pass: 4x unroll, single coalesced record stream ----------------
__global__ __launch_bounds__(256) void item_pass(const int* __restrict__ off_all,
                                                 const __bf16* __restrict__ ub_emb,
                                                 const __bf16* __restrict__ pVb,
                                                 const __bf16* __restrict__ ipk,
                                                 const float4* __restrict__ mb_rec,
                                                 __bf16* __restrict__ B1n, __bf16* __restrict__ PVn,
                                                 __bf16* __restrict__ B2n, int nu, int ni, int imax, int E) {
    int it = blockIdx.x * 4 + (threadIdx.x >> 6);
    if (it >= ni) return;
    int lane = threadIdx.x & 63;
    int g = lane >> 4, l16 = lane & 15;
    int ioff = off_all[nu + it] - E, n = off_all[nu + it + 1] - E - ioff;
    if (n == 0) {
        if (lane < 16) {
            bf16x8 z = {};
            *(bf16x8*)(B1n + (size_t)it * D_ + l16 * 8) = z;
            *(bf16x8*)(PVn + (size_t)it * D_ + l16 * 8) = z;
            *(bf16x8*)(B2n + (size_t)it * D_ + l16 * 8) = z;
        }
        return;
    }
    const __bf16* ipk_row = ipk + (size_t)it * imax;

    float s1 = 0.f, s2 = 0.f, b1[8] = {}, bpv[8] = {}, b2[8] = {};
    for (int i = g; i < n; i += 16) {
        float4 rec[4];
        bool ok[4];
#pragma unroll
        for (int s = 0; s < 4; s++) {
            int ii = i + 4 * s;
            ok[s] = ii < n;
            rec[s] = mb_rec[ioff + (ok[s] ? ii : i)];
        }
        bf16x8 vue[4], vpv[4];
#pragma unroll
        for (int s = 0; s < 4; s++) {
            int pa = __float_as_int(rec[s].z);
            int uA = pa & 0x3FFFF, r1 = (pa >> 18) & 0x3F;
            vue[s] = ((const bf16x8*)(ub_emb + (size_t)uA * D_))[l16];
            vpv[s] = ((const bf16x8*)(pVb + (size_t)r1 * D_))[l16];
        }
#pragma unroll
        for (int s = 0; s < 4; s++) {
            int pa = __float_as_int(rec[s].z);
            int r2 = (pa >> 24) & 0x3F;
            float w1 = ok[s] ? __expf(rec[s].x + bf2f(ipk_row[r2])) : 0.f;
            float w2 = ok[s] ? __expf(rec[s].y) : 0.f;
            s1 += w1; s2 += w2;
            float fue[8], fpv[8];
            unpack8(vue[s], fue);
            unpack8(vpv[s], fpv);
#pragma unroll
            for (int j = 0; j < 8; j++) {
                b1[j]  = fmaf(w1, fue[j], b1[j]);
                bpv[j] = fmaf(w1, fpv[j], bpv[j]);
                b2[j]  = fmaf(w2, fue[j], b2[j]);
            }
        }
    }
#pragma unroll
    for (int d = 16; d < 64; d <<= 1) {
        s1 += __shfl_xor(s1, d); s2 += __shfl_xor(s2, d);
#pragma unroll
        for (int j = 0; j < 8; j++) {
            b1[j]  += __shfl_xor(b1[j], d);
            bpv[j] += __shfl_xor(bpv[j], d);
            b2[j]  += __shfl_xor(b2[j], d);
        }
    }
    if (lane < 16) {
        float inv1 = 1.f / s1, inv2 = 1.f / s2;
        *(bf16x8*)(B1n + (size_t)it * D_ + l16 * 8) = pack8(b1, inv1);
        *(bf16x8*)(PVn + (size_t)it * D_ + l16 * 8) = pack8(bpv, inv1);
        *(bf16x8*)(B2n + (size_t)it * D_ + l16 * 8) = pack8(b2, inv2);
    }
}

// ---------------- finish GEMM (4 configs via blockIdx.y), swapped-operand direct-store epilogue ----------------
struct FinArgs { const __bf16* A; const __bf16* W; const __bf16* side; const int* offseg; float* out; int rows; };
struct Fin4 { FinArgs f[4]; };
__global__ __launch_bounds__(256) void finish4(Fin4 fa) {
    FinArgs q = fa.f[blockIdx.y];
    if (blockIdx.x * 256 >= (unsigned)q.rows) return;
    __shared__ __bf16 sW[128][136];
    int t = threadIdx.x;
#pragma unroll
    for (int it = 0; it < 8; it++) {
        int slot = it * 256 + t;
        int r = slot >> 4, c16 = (slot & 15) * 8;
        bf16x8 v = *(const bf16x8*)(q.W + (size_t)r * D_ + c16);
        *(bf16x8*)(&sW[r][c16]) = v;
    }
    __syncthreads();
    int lane = t & 63, wave = t >> 6;
    int l16 = lane & 15, kh = lane >> 4;

    for (int tt = 0; tt < 4; tt++) {
        int rowblk = blockIdx.x * 256 + (tt * 4 + wave) * 16;
        if (rowblk >= q.rows) break;
        int ar = rowblk + l16;
        bool rok = ar < q.rows;
        int arc = rok ? ar : q.rows - 1;
        const __bf16* rA = q.A + (size_t)arc * D_;
        bf16x8 b0 = *(const bf16x8*)(rA + kh * 8);
        bf16x8 b1 = *(const bf16x8*)(rA + 32 + kh * 8);
        bf16x8 b2 = *(const bf16x8*)(rA + 64 + kh * 8);
        bf16x8 b3 = *(const bf16x8*)(rA + 96 + kh * 8);
        float addv = 0.f;
        if (!q.side && rok) addv = (q.offseg[ar + 1] - q.offseg[ar]) > 0 ? 1.f : 0.f;
#pragma unroll
        for (int cc = 0; cc < 8; cc++) {
            int wr = cc * 16 + l16;
            f32x4 acc = {};
            acc = __builtin_amdgcn_mfma_f32_16x16x32_bf16(*(const bf16x8*)(&sW[wr][kh * 8]), b0, acc, 0, 0, 0);
            acc = __builtin_amdgcn_mfma_f32_16x16x32_bf16(*(const bf16x8*)(&sW[wr][32 + kh * 8]), b1, acc, 0, 0, 0);
            acc = __builtin_amdgcn_mfma_f32_16x16x32_bf16(*(const bf16x8*)(&sW[wr][64 + kh * 8]), b2, acc, 0, 0, 0);
            acc = __builtin_amdgcn_mfma_f32_16x16x32_bf16(*(const bf16x8*)(&sW[wr][96 + kh * 8]), b3, acc, 0, 0, 0);
            if (rok) {
                int col = cc * 16 + kh * 4;
                float4 v = make_float4(acc[0], acc[1], acc[2], acc[3]);
                if (q.side) {
                    ushort4 sv = *(const ushort4*)((const unsigned short*)q.side + (size_t)ar * D_ + col);
                    v.x += __uint_as_float((uint32_t)sv.x << 16);
                    v.y += __uint_as_float((uint32_t)sv.y << 16);
                    v.z += __uint_as_float((uint32_t)sv.z << 16);
                    v.w += __uint_as_float((uint32_t)sv.w << 16);
                } else {
                    v.x += addv; v.y += addv; v.z += addv; v.w += addv;
                }
                *(float4*)(q.out + (size_t)ar * D_ + col) = v;
            }
        }
    }
}

extern "C" void kernel_launch(void* const* d_in, const int* in_sizes, int n_in,
                              void* d_out, int out_size, void* d_ws, size_t ws_size,
                              hipStream_t stream) {
    (void)n_in; (void)out_size; (void)ws_size;
    const float* u_emb = (const float*)d_in[0];
    const float* i_emb = (const float*)d_in[1];
    const int* edge_u = (const int*)d_in[2];
    const int* edge_i = (const int*)d_in[3];
    const int* rui = (const int*)d_in[4];
    const int* riu = (const int*)d_in[5];
    const int* last_u_items = (const int*)d_in[6];
    const int* last_i_users = (const int*)d_in[7];
    const float* W1  = (const float*)d_in[8];
    const float* W2  = (const float*)d_in[9];
    const float* W1b = (const float*)d_in[10];
    const float* W2b = (const float*)d_in[11];
    const float* W3  = (const float*)d_in[12];
    const float* W4  = (const float*)d_in[13];
    const float* pV  = (const float*)d_in[14];
    const float* pK  = (const float*)d_in[15];
    const float* last_user_table = (const float*)d_in[16];
    const float* last_item_table = (const float*)d_in[17];

    const int NU = in_sizes[0] / D_;
    const int NI = in_sizes[1] / D_;
    const int E  = in_sizes[2];
    const int UMAXr = in_sizes[14] / D_;
    const int IMAXr = in_sizes[15] / D_;
    const int NSEG = NU + NI;

    size_t cur = 0;
    auto alloc = [&](size_t bytes) -> void* {
        void* p = (char*)d_ws + cur;
        cur += (bytes + 255) & ~(size_t)255;
        return p;
    };

    __bf16* Wb4   = (__bf16*)alloc(4 * 16384 * 2);
    __bf16* M2t   = (__bf16*)alloc(16384 * 2);
    __bf16* M3t   = (__bf16*)alloc(16384 * 2);
    __bf16* M4t   = (__bf16*)alloc(16384 * 2);
    __bf16* pVW2  = (__bf16*)alloc((size_t)UMAXr * D_ * 2);
    __bf16* pKW1  = (__bf16*)alloc((size_t)IMAXr * D_ * 2);
    __bf16* pVb   = (__bf16*)alloc((size_t)UMAXr * D_ * 2);
    __bf16* pKb   = (__bf16*)alloc((size_t)IMAXr * D_ * 2);
    __bf16* ub_emb = (__bf16*)alloc((size_t)NU * D_ * 2);
    __bf16* ib_emb = (__bf16*)alloc((size_t)NI * D_ * 2);
    __bf16* um_t  = (__bf16*)alloc((size_t)NU * D_ * 2);
    __bf16* li_t  = (__bf16*)alloc((size_t)NU * D_ * 2);
    __bf16* lu_t  = (__bf16*)alloc((size_t)NU * D_ * 2);
    __bf16* upv   = (__bf16*)alloc((size_t)NU * UMAXr * 2);
    __bf16* ipk   = (__bf16*)alloc((size_t)NI * IMAXr * 2);
    __bf16* A1n   = (__bf16*)alloc((size_t)NU * D_ * 2);
    __bf16* PKn   = (__bf16*)alloc((size_t)NU * D_ * 2);
    __bf16* A2n   = (__bf16*)alloc((size_t)NU * D_ * 2);
    __bf16* B1n   = (__bf16*)alloc((size_t)NI * D_ * 2);
    __bf16* PVn   = (__bf16*)alloc((size_t)NI * D_ * 2);
    __bf16* B2n   = (__bf16*)alloc((size_t)NI * D_ * 2);
    float* mb_rec = (float*)alloc((size_t)E * 16);
    int* u_list   = (int*)alloc((size_t)E * 8);
    int* cnt_all  = (int*)alloc((size_t)NSEG * 4);
    int* off_all  = (int*)alloc((size_t)(NSEG + 1) * 4);
    int* pos_all  = (int*)alloc((size_t)NSEG * 4);
    int* parts    = (int*)alloc(1024 * 4);

    float* out = (float*)d_out;
    float* hLu = out;
    float* hSu = out + (size_t)NU * D_;
    float* hLi = out + (size_t)2 * NU * D_;
    float* hSi = out + (size_t)2 * NU * D_ + (size_t)NI * D_;

    // zero counters first (hist merged into prep_all)
    hipMemsetAsync(cnt_all, 0, (size_t)NSEG * 4, stream);

    // merged prep: weight/p casts + emb casts + histogram
    int npv = UMAXr * D_, npk = IMAXr * D_;
    size_t nue = (size_t)NU * D_, nie = (size_t)NI * D_;
    PrepArgs pa;
    pa.w.p[0] = W1; pa.w.p[1] = W2; pa.w.p[2] = W1b; pa.w.p[3] = W2b;
    pa.pV = pV; pa.pK = pK; pa.outW = Wb4; pa.pVb = pVb; pa.pKb = pKb; pa.npv = npv; pa.npk = npk;
    pa.u_emb = u_emb; pa.i_emb = i_emb; pa.ub = ub_emb; pa.ib = ib_emb; pa.nue = nue; pa.nie = nie;
    pa.eu = edge_u; pa.ei = edge_i; pa.cnt_all = cnt_all; pa.nu = NU; pa.E = E;
    pa.wb_blocks = (4 * 16384 + npv + npk + 255) / 256;
    pa.eb_blocks = (int)(((nue + nie) / 4 + 255) / 256);
    int hb_blocks = (E + 255) / 256;
    prep_all<<<pa.wb_blocks + pa.eb_blocks + hb_blocks, 256, 0, stream>>>(pa);

    prep_mats<<<128 + (UMAXr > IMAXr ? UMAXr : IMAXr), 128, 0, stream>>>(W1, W2, W3, W4, pV, pK,
                                                                         M2t, M3t, M4t, pVW2, pKW1, UMAXr, IMAXr);

    // CSR scan chain
    int nb = (NSEG + SCAN_TILE - 1) / SCAN_TILE;
    scan_phaseA<<<nb, 256, 0, stream>>>(cnt_all, parts, NSEG);
    scan_phaseB<<<1, 1024, 0, stream>>>(parts, nb, off_all, NSEG);
    scan_phaseC<<<nb, 256, 0, stream>>>(cnt_all, parts, off_all, pos_all, NSEG);

    // merged: user vectors + pvk GEMMs + scatter (one launch)
    int gu = (NU + 63) / 64, gi = (NI + 63) / 64;
    int gmax = gu > gi ? gu : gi;
    int sb = (E + 255) / 256;
    int gx = gmax > sb ? gmax : sb;
    VecsPvk vp;
    vp.u_emb = u_emb; vp.lit_tab = last_item_table; vp.g_li = last_u_items;
    vp.lut_tab = last_user_table; vp.g_lu = last_i_users;
    vp.M2t = M2t; vp.M3t = M3t; vp.M4t = M4t;
    vp.um_t = um_t; vp.li_t = li_t; vp.lu_t = lu_t; vp.nu = NU;
    vp.a[0] = {ub_emb, pVW2, upv, NU, UMAXr};
    vp.a[1] = {ib_emb, pKW1, ipk, NI, IMAXr};
    vp.eu = edge_u; vp.ei = edge_i; vp.rui = rui; vp.riu = riu;
    vp.pos_all = pos_all; vp.u_list = u_list; vp.E = E;
    vecs_pvk<<<dim3(gx, 4), 256, 0, stream>>>(vp);

    // edge passes
    user_pass<<<(NU + 3) / 4, 256, 0, stream>>>(off_all, u_list, ib_emb, um_t, li_t, lu_t,
                                                pKb, upv, mb_rec, A1n, PKn, A2n, NU, UMAXr);
    item_pass<<<(NI + 3) / 4, 256, 0, stream>>>(off_all, ub_emb, pVb, ipk, (const float4*)mb_rec,
                                                B1n, PVn, B2n, NU, NI, IMAXr, E);

    // finish projections (one launch, 4 configs)
    int fu = (NU + 255) / 256, fi = (NI + 255) / 256;
    Fin4 fa;
    fa.f[0] = {A1n, Wb4 + 2 * 16384, PKn, nullptr, hLu, NU};
    fa.f[1] = {A2n, Wb4 + 0 * 16384, nullptr, off_all, hSu, NU};
    fa.f[2] = {B1n, Wb4 + 3 * 16384, PVn, nullptr, hLi, NI};
    fa.f[3] = {B2n, Wb4 + 1 * 16384, nullptr, off_all + NU, hSi, NI};
    finish4<<<dim3((fu > fi ? fu : fi), 4), 256, 0, stream>>>(fa);
}

// Round 17
// 506.554 us; speedup vs baseline: 1.0169x; 1.0169x over previous
//
#include <hip/hip_runtime.h>
#include <hip/hip_bf16.h>
#include <math.h>

#define D_ 128
#define INV_SQRT_D 0.08838834764831845f
#define SCAN_CH 16
#define SCAN_TILE (256 * SCAN_CH)

typedef __bf16 bf16x8 __attribute__((ext_vector_type(8)));
typedef float f32x4 __attribute__((ext_vector_type(4)));
typedef int i32x2 __attribute__((ext_vector_type(2)));

struct W4p { const float* p[4]; };

__device__ __forceinline__ void unpack8(bf16x8 v, float* f) {
    const uint32_t* u = (const uint32_t*)&v;
#pragma unroll
    for (int i = 0; i < 4; i++) {
        uint32_t w = u[i];
        f[2 * i]     = __uint_as_float(w << 16);
        f[2 * i + 1] = __uint_as_float(w & 0xffff0000u);
    }
}

__device__ __forceinline__ bf16x8 pack8(const float* f, float s) {
    bf16x8 r;
#pragma unroll
    for (int j = 0; j < 8; j++) r[j] = (__bf16)(f[j] * s);
    return r;
}

__device__ __forceinline__ float bf2f(__bf16 v) {
    return __uint_as_float((uint32_t)(*(unsigned short*)&v) << 16);
}

// ---------------- merged prep: weight/p-table casts + emb casts + edge histogram ----------------
struct PrepArgs {
    W4p w; const float* pV; const float* pK;
    __bf16* outW; __bf16* pVb; __bf16* pKb; int npv; int npk;
    const float* u_emb; const float* i_emb; __bf16* ub; __bf16* ib;
    size_t nue; size_t nie;
    const int* eu; const int* ei; int* cnt_all; int nu; int E;
    int wb_blocks; int eb_blocks;
};
__global__ __launch_bounds__(256) void prep_all(PrepArgs a) {
    int b = blockIdx.x;
    if (b < a.wb_blocks) {
        int idx = b * 256 + threadIdx.x;
        if (idx < 4 * 16384) {
            a.outW[idx] = (__bf16)a.w.p[idx >> 14][idx & 16383];
        } else if (idx - 4 * 16384 < a.npv) {
            int j = idx - 4 * 16384;
            a.pVb[j] = (__bf16)a.pV[j];
        } else if (idx - 4 * 16384 - a.npv < a.npk) {
            int j = idx - 4 * 16384 - a.npv;
            a.pKb[j] = (__bf16)a.pK[j];
        }
    } else if (b < a.wb_blocks + a.eb_blocks) {
        size_t idx4 = ((size_t)(b - a.wb_blocks) * 256 + threadIdx.x) * 4;
        if (idx4 < a.nue) {
            float4 v = *(const float4*)(a.u_emb + idx4);
            a.ub[idx4] = (__bf16)v.x; a.ub[idx4+1] = (__bf16)v.y; a.ub[idx4+2] = (__bf16)v.z; a.ub[idx4+3] = (__bf16)v.w;
        } else if (idx4 < a.nue + a.nie) {
            size_t j = idx4 - a.nue;
            float4 v = *(const float4*)(a.i_emb + j);
            a.ib[j] = (__bf16)v.x; a.ib[j+1] = (__bf16)v.y; a.ib[j+2] = (__bf16)v.z; a.ib[j+3] = (__bf16)v.w;
        }
    } else {
        int e = (b - a.wb_blocks - a.eb_blocks) * 256 + threadIdx.x;
        if (e < a.E) {
            atomicAdd(&a.cnt_all[a.eu[e]], 1);
            atomicAdd(&a.cnt_all[a.nu + a.ei[e]], 1);
        }
    }
}

// ---------------- combined-matrix prep ----------------
__global__ __launch_bounds__(128) void prep_mats(const float* __restrict__ W1, const float* __restrict__ W2,
                                                 const float* __restrict__ W3, const float* __restrict__ W4,
                                                 const float* __restrict__ pV, const float* __restrict__ pK,
                                                 __bf16* __restrict__ M2t, __bf16* __restrict__ M3t,
                                                 __bf16* __restrict__ M4t,
                                                 __bf16* __restrict__ pVW2, __bf16* __restrict__ pKW1,
                                                 int umax, int imax) {
    __shared__ float sh[256];
    int b = blockIdx.x, t = threadIdx.x;
    if (b < 128) {
        sh[t] = W1[t * 128 + b];
        __syncthreads();
        float m2 = 0.f, m3 = 0.f, m4 = 0.f;
        for (int k = 0; k < 128; k++) {
            float w = sh[k];
            m2 = fmaf(w, W2[k * 128 + t], m2);
            m3 = fmaf(w, W3[k * 128 + t], m3);
            m4 = fmaf(w, W4[k * 128 + t], m4);
        }
        M2t[b * 128 + t] = (__bf16)(m2 * INV_SQRT_D);
        M3t[b * 128 + t] = (__bf16)(m3 * INV_SQRT_D);
        M4t[b * 128 + t] = (__bf16)(m4 * INV_SQRT_D);
    } else {
        int r = b - 128;
        if (r < umax) sh[t] = pV[r * 128 + t];
        if (r < imax) sh[128 + t] = pK[r * 128 + t];
        __syncthreads();
        float q = 0.f, qk = 0.f;
        for (int a = 0; a < 128; a++) {
            if (r < umax) q  = fmaf(sh[a], W2[a * 128 + t], q);
            if (r < imax) qk = fmaf(sh[128 + a], W1[a * 128 + t], qk);
        }
        if (r < umax) pVW2[r * 128 + t] = (__bf16)(q * INV_SQRT_D);
        if (r < imax) pKW1[r * 128 + t] = (__bf16)(qk * INV_SQRT_D);
    }
}

// ---------------- merged: user vectors (y=0) + pvk GEMMs (y=1,2) ----------------
struct PvkA { const __bf16* X; const __bf16* P; __bf16* Y; int rows; int ncols; };
struct VecsPvk {
    const float* u_emb; const float* lit_tab; const int* g_li;
    const float* lut_tab; const int* g_lu;
    const __bf16* M2t; const __bf16* M3t; const __bf16* M4t;
    __bf16* um_t; __bf16* li_t; __bf16* lu_t; int nu;
    PvkA a[2];
};
__global__ __launch_bounds__(256) void vecs_pvk(VecsPvk p) {
    int lane = threadIdx.x & 63;
    int wave = threadIdx.x >> 6;
    int row0 = blockIdx.x * 64 + wave * 16;
    int l16 = lane & 15, kh = lane >> 4;
    if (blockIdx.y == 0) {
        int rows = p.nu;
        if (row0 >= rows) return;
        int ar = row0 + l16;
        int arc = ar < rows ? ar : rows - 1;
        const float* rA = p.u_emb + (size_t)arc * D_;
        const float* rB = p.lit_tab + (size_t)p.g_li[arc] * D_;
        const float* rC = p.lut_tab + (size_t)p.g_lu[arc] * D_;

        f32x4 aA[8] = {}, aB[8] = {}, aC[8] = {};
#pragma unroll
        for (int k0 = 0; k0 < D_; k0 += 32) {
            int kk = k0 + kh * 8;
            float4 a0 = *(const float4*)(rA + kk), a1 = *(const float4*)(rA + kk + 4);
            float4 b0 = *(const float4*)(rB + kk), b1 = *(const float4*)(rB + kk + 4);
            float4 c0 = *(const float4*)(rC + kk), c1 = *(const float4*)(rC + kk + 4);
            bf16x8 fA, fB, fC;
            fA[0]=(__bf16)a0.x; fA[1]=(__bf16)a0.y; fA[2]=(__bf16)a0.z; fA[3]=(__bf16)a0.w;
            fA[4]=(__bf16)a1.x; fA[5]=(__bf16)a1.y; fA[6]=(__bf16)a1.z; fA[7]=(__bf16)a1.w;
            fB[0]=(__bf16)b0.x; fB[1]=(__bf16)b0.y; fB[2]=(__bf16)b0.z; fB[3]=(__bf16)b0.w;
            fB[4]=(__bf16)b1.x; fB[5]=(__bf16)b1.y; fB[6]=(__bf16)b1.z; fB[7]=(__bf16)b1.w;
            fC[0]=(__bf16)c0.x; fC[1]=(__bf16)c0.y; fC[2]=(__bf16)c0.z; fC[3]=(__bf16)c0.w;
            fC[4]=(__bf16)c1.x; fC[5]=(__bf16)c1.y; fC[6]=(__bf16)c1.z; fC[7]=(__bf16)c1.w;
#pragma unroll
            for (int cb = 0; cb < 8; cb++) {
                bf16x8 w2 = *(const bf16x8*)(p.M2t + (size_t)(cb * 16 + l16) * D_ + kk);
                aA[cb] = __builtin_amdgcn_mfma_f32_16x16x32_bf16(fA, w2, aA[cb], 0, 0, 0);
                bf16x8 w3 = *(const bf16x8*)(p.M3t + (size_t)(cb * 16 + l16) * D_ + kk);
                aB[cb] = __builtin_amdgcn_mfma_f32_16x16x32_bf16(fB, w3, aB[cb], 0, 0, 0);
                bf16x8 w4 = *(const bf16x8*)(p.M4t + (size_t)(cb * 16 + l16) * D_ + kk);
                aC[cb] = __builtin_amdgcn_mfma_f32_16x16x32_bf16(fC, w4, aC[cb], 0, 0, 0);
            }
        }
#pragma unroll
        for (int cb = 0; cb < 8; cb++) {
#pragma unroll
            for (int j = 0; j < 4; j++) {
                int r = row0 + kh * 4 + j;
                if (r < rows) {
                    p.um_t[(size_t)r * D_ + cb * 16 + l16] = (__bf16)aA[cb][j];
                    p.li_t[(size_t)r * D_ + cb * 16 + l16] = (__bf16)aB[cb][j];
                    p.lu_t[(size_t)r * D_ + cb * 16 + l16] = (__bf16)aC[cb][j];
                }
            }
        }
    } else {
        PvkA q = p.a[blockIdx.y - 1];
        if (row0 >= q.rows) return;
        int ar = row0 + l16;
        int arc = ar < q.rows ? ar : q.rows - 1;
        const __bf16* arow = q.X + (size_t)arc * D_;

        f32x4 acc[4] = {};
#pragma unroll
        for (int k0 = 0; k0 < D_; k0 += 32) {
            int kk = k0 + kh * 8;
            bf16x8 af = *(const bf16x8*)(arow + kk);
#pragma unroll
            for (int cb = 0; cb < 4; cb++) {
                int br = cb * 16 + l16;
                if (br >= q.ncols) br = q.ncols - 1;
                bf16x8 bf = *(const bf16x8*)(q.P + (size_t)br * D_ + kk);
                acc[cb] = __builtin_amdgcn_mfma_f32_16x16x32_bf16(af, bf, acc[cb], 0, 0, 0);
            }
        }
#pragma unroll
        for (int cb = 0; cb < 4; cb++) {
            int col = cb * 16 + l16;
            if (col >= q.ncols) continue;
#pragma unroll
            for (int j = 0; j < 4; j++) {
                int r = row0 + kh * 4 + j;
                if (r < q.rows) q.Y[(size_t)r * q.ncols + col] = (__bf16)acc[cb][j];
            }
        }
    }
}

// ---------------- scans ----------------
__global__ __launch_bounds__(256) void scan_phaseA(const int* __restrict__ cnt, int* __restrict__ part, int n) {
    __shared__ int wsum[4];
    int t = threadIdx.x, lane = t & 63, w = t >> 6;
    int i0 = blockIdx.x * SCAN_TILE + t * SCAN_CH;
    int tot = 0;
#pragma unroll
    for (int j = 0; j < SCAN_CH; j++) tot += (i0 + j < n) ? cnt[i0 + j] : 0;
#pragma unroll
    for (int d = 32; d; d >>= 1) tot += __shfl_xor(tot, d);
    if (lane == 0) wsum[w] = tot;
    __syncthreads();
    if (t == 0) part[blockIdx.x] = wsum[0] + wsum[1] + wsum[2] + wsum[3];
}

__global__ __launch_bounds__(1024) void scan_phaseB(int* __restrict__ part, int nb,
                                                    int* __restrict__ off, int n) {
    __shared__ int wsum[16];
    int t = threadIdx.x, lane = t & 63, w = t >> 6;
    int v = (t < nb) ? part[t] : 0;
    int x = v;
#pragma unroll
    for (int d = 1; d < 64; d <<= 1) {
        int y = __shfl_up(x, d);
        if (lane >= d) x += y;
    }
    if (lane == 63) wsum[w] = x;
    __syncthreads();
    int wbase = 0;
    for (int ww = 0; ww < w; ww++) wbase += wsum[ww];
    if (t < nb) part[t] = wbase + x - v;
    if (t == 1023) off[n] = wbase + x;
}

__global__ __launch_bounds__(256) void scan_phaseC(const int* __restrict__ cnt, const int* __restrict__ part,
                                                   int* __restrict__ off, int* __restrict__ pos, int n) {
    __shared__ int wsum[4];
    int t = threadIdx.x, lane = t & 63, w = t >> 6;
    int i0 = blockIdx.x * SCAN_TILE + t * SCAN_CH;
    int loc[SCAN_CH];
    int tot = 0;
#pragma unroll
    for (int j = 0; j < SCAN_CH; j++) {
        int v = (i0 + j < n) ? cnt[i0 + j] : 0;
        loc[j] = tot; tot += v;
    }
    int x = tot;
#pragma unroll
    for (int d = 1; d < 64; d <<= 1) {
        int y = __shfl_up(x, d);
        if (lane >= d) x += y;
    }
    if (lane == 63) wsum[w] = x;
    __syncthreads();
    int wbase = 0;
    for (int ww = 0; ww < w; ww++) wbase += wsum[ww];
    int excl = part[blockIdx.x] + wbase + x - tot;
#pragma unroll
    for (int j = 0; j < SCAN_CH; j++) {
        if (i0 + j < n) { off[i0 + j] = excl + loc[j]; pos[i0 + j] = excl + loc[j]; }
    }
}

// ---------------- scatter (standalone, low-VGPR, high occupancy) ----------------
__global__ __launch_bounds__(256) void scatter2(const int* __restrict__ eu, const int* __restrict__ ei,
                                                const int* __restrict__ rui, const int* __restrict__ riu,
                                                int* __restrict__ pos_all, int* __restrict__ u_list,
                                                int nu, int E) {
    int e = blockIdx.x * 256 + threadIdx.x;
    if (e < E) {
        int u = eu[e], it = ei[e], r1 = rui[e], r2 = riu[e];
        int rbits = (r1 << 18) | (r2 << 24);
        int pi = atomicAdd(&pos_all[nu + it], 1) - E;
        int pu = atomicAdd(&pos_all[u], 1);
        i32x2 rec;
        rec[0] = it | rbits;
        rec[1] = pi;
        __builtin_nontemporal_store(rec, (i32x2*)(u_list + (size_t)pu * 2));
    }
}

// ---------------- user pass: 4x unroll, gathers issued up-front ----------------
__global__ __launch_bounds__(256) void user_pass(const int* __restrict__ off_all, const int* __restrict__ u_list,
                                                 const __bf16* __restrict__ ib_emb,
                                                 const __bf16* __restrict__ um_t,
                                                 const __bf16* __restrict__ li_t,
                                                 const __bf16* __restrict__ lu_t,
                                                 const __bf16* __restrict__ pKb,
                                                 const __bf16* __restrict__ upv,
                                                 float* __restrict__ mb_rec,
                                                 __bf16* __restrict__ A1n, __bf16* __restrict__ PKn,
                                                 __bf16* __restrict__ A2n, int nu, int umax) {
    int u = blockIdx.x * 4 + (threadIdx.x >> 6);
    if (u >= nu) return;
    int lane = threadIdx.x & 63;
    int g = lane >> 4, l16 = lane & 15;
    int off = off_all[u], n = off_all[u + 1] - off;
    if (n == 0) {
        if (lane < 16) {
            bf16x8 z = {};
            *(bf16x8*)(A1n + (size_t)u * D_ + l16 * 8) = z;
            *(bf16x8*)(PKn + (size_t)u * D_ + l16 * 8) = z;
            *(bf16x8*)(A2n + (size_t)u * D_ + l16 * 8) = z;
        }
        return;
    }
    float um8[8], li8[8], lu8[8];
    unpack8(((const bf16x8*)(um_t + (size_t)u * D_))[l16], um8);
    unpack8(((const bf16x8*)(li_t + (size_t)u * D_))[l16], li8);
    unpack8(((const bf16x8*)(lu_t + (size_t)u * D_))[l16], lu8);
    const __bf16* upv_row = upv + (size_t)u * umax;

    float s1 = 0.f, s2 = 0.f, a1[8] = {}, apk[8] = {}, a2[8] = {};
    for (int i = g; i < n; i += 16) {
        i32x2 rec[4];
        bool ok[4];
#pragma unroll
        for (int s = 0; s < 4; s++) {
            int ii = i + 4 * s;
            ok[s] = ii < n;
            rec[s] = *(const i32x2*)(u_list + (size_t)(off + (ok[s] ? ii : i)) * 2);
        }
        bf16x8 vie[4], vpk[4];
#pragma unroll
        for (int s = 0; s < 4; s++) {
            int it = rec[s][0] & 0x3FFFF;
            int r2 = (rec[s][0] >> 24) & 0x3F;
            vie[s] = ((const bf16x8*)(ib_emb + (size_t)it * D_))[l16];
            vpk[s] = ((const bf16x8*)(pKb + (size_t)r2 * D_))[l16];
        }
#pragma unroll
        for (int s = 0; s < 4; s++) {
            float fie[8];
            unpack8(vie[s], fie);
            float d1 = 0.f, d2 = 0.f, d3 = 0.f;
#pragma unroll
            for (int j = 0; j < 8; j++) {
                d1 = fmaf(um8[j], fie[j], d1);
                d2 = fmaf(li8[j], fie[j], d2);
                d3 = fmaf(lu8[j], fie[j], d3);
            }
#pragma unroll
            for (int d = 1; d < 16; d <<= 1) {
                d1 += __shfl_xor(d1, d);
                d2 += __shfl_xor(d2, d);
                d3 += __shfl_xor(d3, d);
            }
            if (l16 == 0 && ok[s]) {
                f32x4 r;
                r[0] = d1; r[1] = d3;
                r[2] = __int_as_float(u | (rec[s][0] & 0x3FFC0000)); r[3] = 0.f;
                __builtin_nontemporal_store(r, (f32x4*)(mb_rec + (size_t)rec[s][1] * 4));
            }
            int r1 = (rec[s][0] >> 18) & 0x3F;
            float w1 = ok[s] ? __expf(d1 + bf2f(upv_row[r1])) : 0.f;
            float w2 = ok[s] ? __expf(d2) : 0.f;
            s1 += w1; s2 += w2;
            float fpk[8];
            unpack8(vpk[s], fpk);
#pragma unroll
            for (int j = 0; j < 8; j++) {
                a1[j]  = fmaf(w1, fie[j], a1[j]);
                apk[j] = fmaf(w1, fpk[j], apk[j]);
                a2[j]  = fmaf(w2, fie[j], a2[j]);
            }
        }
    }
#pragma unroll
    for (int d = 16; d < 64; d <<= 1) {
        s1 += __shfl_xor(s1, d); s2 += __shfl_xor(s2, d);
#pragma unroll
        for (int j = 0; j < 8; j++) {
            a1[j]  += __shfl_xor(a1[j], d);
            apk[j] += __shfl_xor(apk[j], d);
            a2[j]  += __shfl_xor(a2[j], d);
        }
    }
    if (lane < 16) {
        float inv1 = 1.f / s1, inv2 = 1.f / s2;
        *(bf16x8*)(A1n + (size_t)u * D_ + l16 * 8) = pack8(a1, inv1);
        *(bf16x8*)(PKn + (size_t)u * D_ + l16 * 8) = pack8(apk, inv1);
        *(bf16x8*)(A2n + (size_t)u * D_ + l16 * 8) = pack8(a2, inv2);
    }
}

// ---------------- item pass: 4x unroll, single coalesced record stream ----------------
__global__ __launch_bounds__(256) void item_pass(const int* __restrict__ off_all,
                                                 const __bf16* __restrict__ ub_emb,
                                                 const __bf16* __restrict__ pVb,
                                                 const __bf16* __restrict__ ipk,
                                                 const float4* __restrict__ mb_rec,
                                                 __bf16* __restrict__ B1n, __bf16* __restrict__ PVn,
                                                 __bf16* __restrict__ B2n, int nu, int ni, int imax, int E) {
    int it = blockIdx.x * 4 + (threadIdx.x >> 6);
    if (it >= ni) return;
    int lane = threadIdx.x & 63;
    int g = lane >> 4, l16 = lane & 15;
    int ioff = off_all[nu + it] - E, n = off_all[nu + it + 1] - E - ioff;
    if (n == 0) {
        if (lane < 16) {
            bf16x8 z = {};
            *(bf16x8*)(B1n + (size_t)it * D_ + l16 * 8) = z;
            *(bf16x8*)(PVn + (size_t)it * D_ + l16 * 8) = z;
            *(bf16x8*)(B2n + (size_t)it * D_ + l16 * 8) = z;
        }
        return;
    }
    const __bf16* ipk_row = ipk + (size_t)it * imax;

    float s1 = 0.f, s2 = 0.f, b1[8] = {}, bpv[8] = {}, b2[8] = {};
    for (int i = g; i < n; i += 16) {
        float4 rec[4];
        bool ok[4];
#pragma unroll
        for (int s = 0; s < 4; s++) {
            int ii = i + 4 * s;
            ok[s] = ii < n;
            rec[s] = mb_rec[ioff + (ok[s] ? ii : i)];
        }
        bf16x8 vue[4], vpv[4];
#pragma unroll
        for (int s = 0; s < 4; s++) {
            int pa = __float_as_int(rec[s].z);
            int uA = pa & 0x3FFFF, r1 = (pa >> 18) & 0x3F;
            vue[s] = ((const bf16x8*)(ub_emb + (size_t)uA * D_))[l16];
            vpv[s] = ((const bf16x8*)(pVb + (size_t)r1 * D_))[l16];
        }
#pragma unroll
        for (int s = 0; s < 4; s++) {
            int pa = __float_as_int(rec[s].z);
            int r2 = (pa >> 24) & 0x3F;
            float w1 = ok[s] ? __expf(rec[s].x + bf2f(ipk_row[r2])) : 0.f;
            float w2 = ok[s] ? __expf(rec[s].y) : 0.f;
            s1 += w1; s2 += w2;
            float fue[8], fpv[8];
            unpack8(vue[s], fue);
            unpack8(vpv[s], fpv);
#pragma unroll
            for (int j = 0; j < 8; j++) {
                b1[j]  = fmaf(w1, fue[j], b1[j]);
                bpv[j] = fmaf(w1, fpv[j], bpv[j]);
                b2[j]  = fmaf(w2, fue[j], b2[j]);
            }
        }
    }
#pragma unroll
    for (int d = 16; d < 64; d <<= 1) {
        s1 += __shfl_xor(s1, d); s2 += __shfl_xor(s2, d);
#pragma unroll
        for (int j = 0; j < 8; j++) {
            b1[j]  += __shfl_xor(b1[j], d);
            bpv[j] += __shfl_xor(bpv[j], d);
            b2[j]  += __shfl_xor(b2[j], d);
        }
    }
    if (lane < 16) {
        float inv1 = 1.f / s1, inv2 = 1.f / s2;
        *(bf16x8*)(B1n + (size_t)it * D_ + l16 * 8) = pack8(b1, inv1);
        *(bf16x8*)(PVn + (size_t)it * D_ + l16 * 8) = pack8(bpv, inv1);
        *(bf16x8*)(B2n + (size_t)it * D_ + l16 * 8) = pack8(b2, inv2);
    }
}

// ---------------- finish GEMM (4 configs via blockIdx.y), swapped-operand direct-store epilogue ----------------
struct FinArgs { const __bf16* A; const __bf16* W; const __bf16* side; const int* offseg; float* out; int rows; };
struct Fin4 { FinArgs f[4]; };
__global__ __launch_bounds__(256) void finish4(Fin4 fa) {
    FinArgs q = fa.f[blockIdx.y];
    if (blockIdx.x * 256 >= (unsigned)q.rows) return;
    __shared__ __bf16 sW[128][136];
    int t = threadIdx.x;
#pragma unroll
    for (int it = 0; it < 8; it++) {
        int slot = it * 256 + t;
        int r = slot >> 4, c16 = (slot & 15) * 8;
        bf16x8 v = *(const bf16x8*)(q.W + (size_t)r * D_ + c16);
        *(bf16x8*)(&sW[r][c16]) = v;
    }
    __syncthreads();
    int lane = t & 63, wave = t >> 6;
    int l16 = lane & 15, kh = lane >> 4;

    for (int tt = 0; tt < 4; tt++) {
        int rowblk = blockIdx.x * 256 + (tt * 4 + wave) * 16;
        if (rowblk >= q.rows) break;
        int ar = rowblk + l16;
        bool rok = ar < q.rows;
        int arc = rok ? ar : q.rows - 1;
        const __bf16* rA = q.A + (size_t)arc * D_;
        bf16x8 b0 = *(const bf16x8*)(rA + kh * 8);
        bf16x8 b1 = *(const bf16x8*)(rA + 32 + kh * 8);
        bf16x8 b2 = *(const bf16x8*)(rA + 64 + kh * 8);
        bf16x8 b3 = *(const bf16x8*)(rA + 96 + kh * 8);
        float addv = 0.f;
        if (!q.side && rok) addv = (q.offseg[ar + 1] - q.offseg[ar]) > 0 ? 1.f : 0.f;
#pragma unroll
        for (int cc = 0; cc < 8; cc++) {
            int wr = cc * 16 + l16;
            f32x4 acc = {};
            acc = __builtin_amdgcn_mfma_f32_16x16x32_bf16(*(const bf16x8*)(&sW[wr][kh * 8]), b0, acc, 0, 0, 0);
            acc = __builtin_amdgcn_mfma_f32_16x16x32_bf16(*(const bf16x8*)(&sW[wr][32 + kh * 8]), b1, acc, 0, 0, 0);
            acc = __builtin_amdgcn_mfma_f32_16x16x32_bf16(*(const bf16x8*)(&sW[wr][64 + kh * 8]), b2, acc, 0, 0, 0);
            acc = __builtin_amdgcn_mfma_f32_16x16x32_bf16(*(const bf16x8*)(&sW[wr][96 + kh * 8]), b3, acc, 0, 0, 0);
            if (rok) {
                int col = cc * 16 + kh * 4;
                float4 v = make_float4(acc[0], acc[1], acc[2], acc[3]);
                if (q.side) {
                    ushort4 sv = *(const ushort4*)((const unsigned short*)q.side + (size_t)ar * D_ + col);
                    v.x += __uint_as_float((uint32_t)sv.x << 16);
                    v.y += __uint_as_float((uint32_t)sv.y << 16);
                    v.z += __uint_as_float((uint32_t)sv.z << 16);
                    v.w += __uint_as_float((uint32_t)sv.w << 16);
                } else {
                    v.x += addv; v.y += addv; v.z += addv; v.w += addv;
                }
                *(float4*)(q.out + (size_t)ar * D_ + col) = v;
            }
        }
    }
}

extern "C" void kernel_launch(void* const* d_in, const int* in_sizes, int n_in,
                              void* d_out, int out_size, void* d_ws, size_t ws_size,
                              hipStream_t stream) {
    (void)n_in; (void)out_size; (void)ws_size;
    const float* u_emb = (const float*)d_in[0];
    const float* i_emb = (const float*)d_in[1];
    const int* edge_u = (const int*)d_in[2];
    const int* edge_i = (const int*)d_in[3];
    const int* rui = (const int*)d_in[4];
    const int* riu = (const int*)d_in[5];
    const int* last_u_items = (const int*)d_in[6];
    const int* last_i_users = (const int*)d_in[7];
    const float* W1  = (const float*)d_in[8];
    const float* W2  = (const float*)d_in[9];
    const float* W1b = (const float*)d_in[10];
    const float* W2b = (const float*)d_in[11];
    const float* W3  = (const float*)d_in[12];
    const float* W4  = (const float*)d_in[13];
    const float* pV  = (const float*)d_in[14];
    const float* pK  = (const float*)d_in[15];
    const float* last_user_table = (const float*)d_in[16];
    const float* last_item_table = (const float*)d_in[17];

    const int NU = in_sizes[0] / D_;
    const int NI = in_sizes[1] / D_;
    const int E  = in_sizes[2];
    const int UMAXr = in_sizes[14] / D_;
    const int IMAXr = in_sizes[15] / D_;
    const int NSEG = NU + NI;

    size_t cur = 0;
    auto alloc = [&](size_t bytes) -> void* {
        void* p = (char*)d_ws + cur;
        cur += (bytes + 255) & ~(size_t)255;
        return p;
    };

    __bf16* Wb4   = (__bf16*)alloc(4 * 16384 * 2);
    __bf16* M2t   = (__bf16*)alloc(16384 * 2);
    __bf16* M3t   = (__bf16*)alloc(16384 * 2);
    __bf16* M4t   = (__bf16*)alloc(16384 * 2);
    __bf16* pVW2  = (__bf16*)alloc((size_t)UMAXr * D_ * 2);
    __bf16* pKW1  = (__bf16*)alloc((size_t)IMAXr * D_ * 2);
    __bf16* pVb   = (__bf16*)alloc((size_t)UMAXr * D_ * 2);
    __bf16* pKb   = (__bf16*)alloc((size_t)IMAXr * D_ * 2);
    __bf16* ub_emb = (__bf16*)alloc((size_t)NU * D_ * 2);
    __bf16* ib_emb = (__bf16*)alloc((size_t)NI * D_ * 2);
    __bf16* um_t  = (__bf16*)alloc((size_t)NU * D_ * 2);
    __bf16* li_t  = (__bf16*)alloc((size_t)NU * D_ * 2);
    __bf16* lu_t  = (__bf16*)alloc((size_t)NU * D_ * 2);
    __bf16* upv   = (__bf16*)alloc((size_t)NU * UMAXr * 2);
    __bf16* ipk   = (__bf16*)alloc((size_t)NI * IMAXr * 2);
    __bf16* A1n   = (__bf16*)alloc((size_t)NU * D_ * 2);
    __bf16* PKn   = (__bf16*)alloc((size_t)NU * D_ * 2);
    __bf16* A2n   = (__bf16*)alloc((size_t)NU * D_ * 2);
    __bf16* B1n   = (__bf16*)alloc((size_t)NI * D_ * 2);
    __bf16* PVn   = (__bf16*)alloc((size_t)NI * D_ * 2);
    __bf16* B2n   = (__bf16*)alloc((size_t)NI * D_ * 2);
    float* mb_rec = (float*)alloc((size_t)E * 16);
    int* u_list   = (int*)alloc((size_t)E * 8);
    int* cnt_all  = (int*)alloc((size_t)NSEG * 4);
    int* off_all  = (int*)alloc((size_t)(NSEG + 1) * 4);
    int* pos_all  = (int*)alloc((size_t)NSEG * 4);
    int* parts    = (int*)alloc(1024 * 4);

    float* out = (float*)d_out;
    float* hLu = out;
    float* hSu = out + (size_t)NU * D_;
    float* hLi = out + (size_t)2 * NU * D_;
    float* hSi = out + (size_t)2 * NU * D_ + (size_t)NI * D_;

    // zero counters first (hist merged into prep_all)
    hipMemsetAsync(cnt_all, 0, (size_t)NSEG * 4, stream);

    // merged prep: weight/p casts + emb casts + histogram
    int npv = UMAXr * D_, npk = IMAXr * D_;
    size_t nue = (size_t)NU * D_, nie = (size_t)NI * D_;
    PrepArgs pa;
    pa.w.p[0] = W1; pa.w.p[1] = W2; pa.w.p[2] = W1b; pa.w.p[3] = W2b;
    pa.pV = pV; pa.pK = pK; pa.outW = Wb4; pa.pVb = pVb; pa.pKb = pKb; pa.npv = npv; pa.npk = npk;
    pa.u_emb = u_emb; pa.i_emb = i_emb; pa.ub = ub_emb; pa.ib = ib_emb; pa.nue = nue; pa.nie = nie;
    pa.eu = edge_u; pa.ei = edge_i; pa.cnt_all = cnt_all; pa.nu = NU; pa.E = E;
    pa.wb_blocks = (4 * 16384 + npv + npk + 255) / 256;
    pa.eb_blocks = (int)(((nue + nie) / 4 + 255) / 256);
    int hb_blocks = (E + 255) / 256;
    prep_all<<<pa.wb_blocks + pa.eb_blocks + hb_blocks, 256, 0, stream>>>(pa);

    prep_mats<<<128 + (UMAXr > IMAXr ? UMAXr : IMAXr), 128, 0, stream>>>(W1, W2, W3, W4, pV, pK,
                                                                         M2t, M3t, M4t, pVW2, pKW1, UMAXr, IMAXr);

    // CSR scan chain
    int nb = (NSEG + SCAN_TILE - 1) / SCAN_TILE;
    scan_phaseA<<<nb, 256, 0, stream>>>(cnt_all, parts, NSEG);
    scan_phaseB<<<1, 1024, 0, stream>>>(parts, nb, off_all, NSEG);
    scan_phaseC<<<nb, 256, 0, stream>>>(cnt_all, parts, off_all, pos_all, NSEG);
    scatter2<<<(E + 255) / 256, 256, 0, stream>>>(edge_u, edge_i, rui, riu, pos_all, u_list, NU, E);

    // merged: user vectors + pvk GEMMs (one launch)
    int gu = (NU + 63) / 64, gi = (NI + 63) / 64;
    int gmax = gu > gi ? gu : gi;
    VecsPvk vp;
    vp.u_emb = u_emb; vp.lit_tab = last_item_table; vp.g_li = last_u_items;
    vp.lut_tab = last_user_table; vp.g_lu = last_i_users;
    vp.M2t = M2t; vp.M3t = M3t; vp.M4t = M4t;
    vp.um_t = um_t; vp.li_t = li_t; vp.lu_t = lu_t; vp.nu = NU;
    vp.a[0] = {ub_emb, pVW2, upv, NU, UMAXr};
    vp.a[1] = {ib_emb, pKW1, ipk, NI, IMAXr};
    vecs_pvk<<<dim3(gmax, 3), 256, 0, stream>>>(vp);

    // edge passes
    user_pass<<<(NU + 3) / 4, 256, 0, stream>>>(off_all, u_list, ib_emb, um_t, li_t, lu_t,
                                                pKb, upv, mb_rec, A1n, PKn, A2n, NU, UMAXr);
    item_pass<<<(NI + 3) / 4, 256, 0, stream>>>(off_all, ub_emb, pVb, ipk, (const float4*)mb_rec,
                                                B1n, PVn, B2n, NU, NI, IMAXr, E);

    // finish projections (one launch, 4 configs)
    int fu = (NU + 255) / 256, fi = (NI + 255) / 256;
    Fin4 fa;
    fa.f[0] = {A1n, Wb4 + 2 * 16384, PKn, nullptr, hLu, NU};
    fa.f[1] = {A2n, Wb4 + 0 * 16384, nullptr, off_all, hSu, NU};
    fa.f[2] = {B1n, Wb4 + 3 * 16384, PVn, nullptr, hLi, NI};
    fa.f[3] = {B2n, Wb4 + 1 * 16384, nullptr, off_all + NU, hSi, NI};
    finish4<<<dim3((fu > fi ? fu : fi), 4), 256, 0, stream>>>(fa);
}

// Round 18
// 476.271 us; speedup vs baseline: 1.0815x; 1.0636x over previous
//
#include <hip/hip_runtime.h>
#include <hip/hip_bf16.h>
#include <math.h>

#define D_ 128
#define INV_SQRT_D 0.08838834764831845f
#define SCAN_CH 16
#define SCAN_TILE (256 * SCAN_CH)

typedef __bf16 bf16x8 __attribute__((ext_vector_type(8)));
typedef float f32x4 __attribute__((ext_vector_type(4)));
typedef int i32x2 __attribute__((ext_vector_type(2)));

struct W4p { const float* p[4]; };

__device__ __forceinline__ void unpack8(bf16x8 v, float* f) {
    const uint32_t* u = (const uint32_t*)&v;
#pragma unroll
    for (int i = 0; i < 4; i++) {
        uint32_t w = u[i];
        f[2 * i]     = __uint_as_float(w << 16);
        f[2 * i + 1] = __uint_as_float(w & 0xffff0000u);
    }
}

__device__ __forceinline__ bf16x8 pack8(const float* f, float s) {
    bf16x8 r;
#pragma unroll
    for (int j = 0; j < 8; j++) r[j] = (__bf16)(f[j] * s);
    return r;
}

__device__ __forceinline__ float bf2f(__bf16 v) {
    return __uint_as_float((uint32_t)(*(unsigned short*)&v) << 16);
}

// ---------------- merged prep: weight/p-table casts + emb casts + edge histogram ----------------
struct PrepArgs {
    W4p w; const float* pV; const float* pK;
    __bf16* outW; __bf16* pVb; __bf16* pKb; int npv; int npk;
    const float* u_emb; const float* i_emb; __bf16* ub; __bf16* ib;
    size_t nue; size_t nie;
    const int* eu; const int* ei; int* cnt_all; int nu; int E;
    int wb_blocks; int eb_blocks;
};
__global__ __launch_bounds__(256) void prep_all(PrepArgs a) {
    int b = blockIdx.x;
    if (b < a.wb_blocks) {
        int idx = b * 256 + threadIdx.x;
        if (idx < 4 * 16384) {
            a.outW[idx] = (__bf16)a.w.p[idx >> 14][idx & 16383];
        } else if (idx - 4 * 16384 < a.npv) {
            int j = idx - 4 * 16384;
            a.pVb[j] = (__bf16)a.pV[j];
        } else if (idx - 4 * 16384 - a.npv < a.npk) {
            int j = idx - 4 * 16384 - a.npv;
            a.pKb[j] = (__bf16)a.pK[j];
        }
    } else if (b < a.wb_blocks + a.eb_blocks) {
        size_t idx4 = ((size_t)(b - a.wb_blocks) * 256 + threadIdx.x) * 4;
        if (idx4 < a.nue) {
            float4 v = *(const float4*)(a.u_emb + idx4);
            a.ub[idx4] = (__bf16)v.x; a.ub[idx4+1] = (__bf16)v.y; a.ub[idx4+2] = (__bf16)v.z; a.ub[idx4+3] = (__bf16)v.w;
        } else if (idx4 < a.nue + a.nie) {
            size_t j = idx4 - a.nue;
            float4 v = *(const float4*)(a.i_emb + j);
            a.ib[j] = (__bf16)v.x; a.ib[j+1] = (__bf16)v.y; a.ib[j+2] = (__bf16)v.z; a.ib[j+3] = (__bf16)v.w;
        }
    } else {
        int e = (b - a.wb_blocks - a.eb_blocks) * 256 + threadIdx.x;
        if (e < a.E) {
            atomicAdd(&a.cnt_all[a.eu[e]], 1);
            atomicAdd(&a.cnt_all[a.nu + a.ei[e]], 1);
        }
    }
}

// ---------------- combined-matrix prep ----------------
__global__ __launch_bounds__(128) void prep_mats(const float* __restrict__ W1, const float* __restrict__ W2,
                                                 const float* __restrict__ W3, const float* __restrict__ W4,
                                                 const float* __restrict__ pV, const float* __restrict__ pK,
                                                 __bf16* __restrict__ M2t, __bf16* __restrict__ M3t,
                                                 __bf16* __restrict__ M4t,
                                                 __bf16* __restrict__ pVW2, __bf16* __restrict__ pKW1,
                                                 int umax, int imax) {
    __shared__ float sh[256];
    int b = blockIdx.x, t = threadIdx.x;
    if (b < 128) {
        sh[t] = W1[t * 128 + b];
        __syncthreads();
        float m2 = 0.f, m3 = 0.f, m4 = 0.f;
        for (int k = 0; k < 128; k++) {
            float w = sh[k];
            m2 = fmaf(w, W2[k * 128 + t], m2);
            m3 = fmaf(w, W3[k * 128 + t], m3);
            m4 = fmaf(w, W4[k * 128 + t], m4);
        }
        M2t[b * 128 + t] = (__bf16)(m2 * INV_SQRT_D);
        M3t[b * 128 + t] = (__bf16)(m3 * INV_SQRT_D);
        M4t[b * 128 + t] = (__bf16)(m4 * INV_SQRT_D);
    } else {
        int r = b - 128;
        if (r < umax) sh[t] = pV[r * 128 + t];
        if (r < imax) sh[128 + t] = pK[r * 128 + t];
        __syncthreads();
        float q = 0.f, qk = 0.f;
        for (int a = 0; a < 128; a++) {
            if (r < umax) q  = fmaf(sh[a], W2[a * 128 + t], q);
            if (r < imax) qk = fmaf(sh[128 + a], W1[a * 128 + t], qk);
        }
        if (r < umax) pVW2[r * 128 + t] = (__bf16)(q * INV_SQRT_D);
        if (r < imax) pKW1[r * 128 + t] = (__bf16)(qk * INV_SQRT_D);
    }
}

// ---------------- merged: user vectors (y=0) + pvk GEMMs (y=1,2) ----------------
struct PvkA { const __bf16* X; const __bf16* P; __bf16* Y; int rows; int ncols; };
struct VecsPvk {
    const float* u_emb; const float* lit_tab; const int* g_li;
    const float* lut_tab; const int* g_lu;
    const __bf16* M2t; const __bf16* M3t; const __bf16* M4t;
    __bf16* um_t; __bf16* li_t; __bf16* lu_t; int nu;
    PvkA a[2];
};
__global__ __launch_bounds__(256) void vecs_pvk(VecsPvk p) {
    int lane = threadIdx.x & 63;
    int wave = threadIdx.x >> 6;
    int row0 = blockIdx.x * 64 + wave * 16;
    int l16 = lane & 15, kh = lane >> 4;
    if (blockIdx.y == 0) {
        int rows = p.nu;
        if (row0 >= rows) return;
        int ar = row0 + l16;
        int arc = ar < rows ? ar : rows - 1;
        const float* rA = p.u_emb + (size_t)arc * D_;
        const float* rB = p.lit_tab + (size_t)p.g_li[arc] * D_;
        const float* rC = p.lut_tab + (size_t)p.g_lu[arc] * D_;

        f32x4 aA[8] = {}, aB[8] = {}, aC[8] = {};
#pragma unroll
        for (int k0 = 0; k0 < D_; k0 += 32) {
            int kk = k0 + kh * 8;
            float4 a0 = *(const float4*)(rA + kk), a1 = *(const float4*)(rA + kk + 4);
            float4 b0 = *(const float4*)(rB + kk), b1 = *(const float4*)(rB + kk + 4);
            float4 c0 = *(const float4*)(rC + kk), c1 = *(const float4*)(rC + kk + 4);
            bf16x8 fA, fB, fC;
            fA[0]=(__bf16)a0.x; fA[1]=(__bf16)a0.y; fA[2]=(__bf16)a0.z; fA[3]=(__bf16)a0.w;
            fA[4]=(__bf16)a1.x; fA[5]=(__bf16)a1.y; fA[6]=(__bf16)a1.z; fA[7]=(__bf16)a1.w;
            fB[0]=(__bf16)b0.x; fB[1]=(__bf16)b0.y; fB[2]=(__bf16)b0.z; fB[3]=(__bf16)b0.w;
            fB[4]=(__bf16)b1.x; fB[5]=(__bf16)b1.y; fB[6]=(__bf16)b1.z; fB[7]=(__bf16)b1.w;
            fC[0]=(__bf16)c0.x; fC[1]=(__bf16)c0.y; fC[2]=(__bf16)c0.z; fC[3]=(__bf16)c0.w;
            fC[4]=(__bf16)c1.x; fC[5]=(__bf16)c1.y; fC[6]=(__bf16)c1.z; fC[7]=(__bf16)c1.w;
#pragma unroll
            for (int cb = 0; cb < 8; cb++) {
                bf16x8 w2 = *(const bf16x8*)(p.M2t + (size_t)(cb * 16 + l16) * D_ + kk);
                aA[cb] = __builtin_amdgcn_mfma_f32_16x16x32_bf16(fA, w2, aA[cb], 0, 0, 0);
                bf16x8 w3 = *(const bf16x8*)(p.M3t + (size_t)(cb * 16 + l16) * D_ + kk);
                aB[cb] = __builtin_amdgcn_mfma_f32_16x16x32_bf16(fB, w3, aB[cb], 0, 0, 0);
                bf16x8 w4 = *(const bf16x8*)(p.M4t + (size_t)(cb * 16 + l16) * D_ + kk);
                aC[cb] = __builtin_amdgcn_mfma_f32_16x16x32_bf16(fC, w4, aC[cb], 0, 0, 0);
            }
        }
#pragma unroll
        for (int cb = 0; cb < 8; cb++) {
#pragma unroll
            for (int j = 0; j < 4; j++) {
                int r = row0 + kh * 4 + j;
                if (r < rows) {
                    p.um_t[(size_t)r * D_ + cb * 16 + l16] = (__bf16)aA[cb][j];
                    p.li_t[(size_t)r * D_ + cb * 16 + l16] = (__bf16)aB[cb][j];
                    p.lu_t[(size_t)r * D_ + cb * 16 + l16] = (__bf16)aC[cb][j];
                }
            }
        }
    } else {
        PvkA q = p.a[blockIdx.y - 1];
        if (row0 >= q.rows) return;
        int ar = row0 + l16;
        int arc = ar < q.rows ? ar : q.rows - 1;
        const __bf16* arow = q.X + (size_t)arc * D_;

        f32x4 acc[4] = {};
#pragma unroll
        for (int k0 = 0; k0 < D_; k0 += 32) {
            int kk = k0 + kh * 8;
            bf16x8 af = *(const bf16x8*)(arow + kk);
#pragma unroll
            for (int cb = 0; cb < 4; cb++) {
                int br = cb * 16 + l16;
                if (br >= q.ncols) br = q.ncols - 1;
                bf16x8 bf = *(const bf16x8*)(q.P + (size_t)br * D_ + kk);
                acc[cb] = __builtin_amdgcn_mfma_f32_16x16x32_bf16(af, bf, acc[cb], 0, 0, 0);
            }
        }
#pragma unroll
        for (int cb = 0; cb < 4; cb++) {
            int col = cb * 16 + l16;
            if (col >= q.ncols) continue;
#pragma unroll
            for (int j = 0; j < 4; j++) {
                int r = row0 + kh * 4 + j;
                if (r < q.rows) q.Y[(size_t)r * q.ncols + col] = (__bf16)acc[cb][j];
            }
        }
    }
}

// ---------------- scans ----------------
__global__ __launch_bounds__(256) void scan_phaseA(const int* __restrict__ cnt, int* __restrict__ part, int n) {
    __shared__ int wsum[4];
    int t = threadIdx.x, lane = t & 63, w = t >> 6;
    int i0 = blockIdx.x * SCAN_TILE + t * SCAN_CH;
    int tot = 0;
#pragma unroll
    for (int j = 0; j < SCAN_CH; j++) tot += (i0 + j < n) ? cnt[i0 + j] : 0;
#pragma unroll
    for (int d = 32; d; d >>= 1) tot += __shfl_xor(tot, d);
    if (lane == 0) wsum[w] = tot;
    __syncthreads();
    if (t == 0) part[blockIdx.x] = wsum[0] + wsum[1] + wsum[2] + wsum[3];
}

__global__ __launch_bounds__(1024) void scan_phaseB(int* __restrict__ part, int nb,
                                                    int* __restrict__ off, int n) {
    __shared__ int wsum[16];
    int t = threadIdx.x, lane = t & 63, w = t >> 6;
    int v = (t < nb) ? part[t] : 0;
    int x = v;
#pragma unroll
    for (int d = 1; d < 64; d <<= 1) {
        int y = __shfl_up(x, d);
        if (lane >= d) x += y;
    }
    if (lane == 63) wsum[w] = x;
    __syncthreads();
    int wbase = 0;
    for (int ww = 0; ww < w; ww++) wbase += wsum[ww];
    if (t < nb) part[t] = wbase + x - v;
    if (t == 1023) off[n] = wbase + x;
}

__global__ __launch_bounds__(256) void scan_phaseC(const int* __restrict__ cnt, const int* __restrict__ part,
                                                   int* __restrict__ off, int* __restrict__ pos, int n) {
    __shared__ int wsum[4];
    int t = threadIdx.x, lane = t & 63, w = t >> 6;
    int i0 = blockIdx.x * SCAN_TILE + t * SCAN_CH;
    int loc[SCAN_CH];
    int tot = 0;
#pragma unroll
    for (int j = 0; j < SCAN_CH; j++) {
        int v = (i0 + j < n) ? cnt[i0 + j] : 0;
        loc[j] = tot; tot += v;
    }
    int x = tot;
#pragma unroll
    for (int d = 1; d < 64; d <<= 1) {
        int y = __shfl_up(x, d);
        if (lane >= d) x += y;
    }
    if (lane == 63) wsum[w] = x;
    __syncthreads();
    int wbase = 0;
    for (int ww = 0; ww < w; ww++) wbase += wsum[ww];
    int excl = part[blockIdx.x] + wbase + x - tot;
#pragma unroll
    for (int j = 0; j < SCAN_CH; j++) {
        if (i0 + j < n) { off[i0 + j] = excl + loc[j]; pos[i0 + j] = excl + loc[j]; }
    }
}

// ---------------- scatter (standalone, low-VGPR, high occupancy) ----------------
__global__ __launch_bounds__(256) void scatter2(const int* __restrict__ eu, const int* __restrict__ ei,
                                                const int* __restrict__ rui, const int* __restrict__ riu,
                                                int* __restrict__ pos_all, int* __restrict__ u_list,
                                                int nu, int E) {
    int e = blockIdx.x * 256 + threadIdx.x;
    if (e < E) {
        int u = eu[e], it = ei[e], r1 = rui[e], r2 = riu[e];
        int rbits = (r1 << 18) | (r2 << 24);
        int pi = atomicAdd(&pos_all[nu + it], 1) - E;
        int pu = atomicAdd(&pos_all[u], 1);
        i32x2 rec;
        rec[0] = it | rbits;
        rec[1] = pi;
        __builtin_nontemporal_store(rec, (i32x2*)(u_list + (size_t)pu * 2));
    }
}

// ---------------- user pass: 2x unroll ----------------
__global__ __launch_bounds__(256) void user_pass(const int* __restrict__ off_all, const int* __restrict__ u_list,
                                                 const __bf16* __restrict__ ib_emb,
                                                 const __bf16* __restrict__ um_t,
                                                 const __bf16* __restrict__ li_t,
                                                 const __bf16* __restrict__ lu_t,
                                                 const __bf16* __restrict__ pKb,
                                                 const __bf16* __restrict__ upv,
                                                 float* __restrict__ mb_rec,
                                                 __bf16* __restrict__ A1n, __bf16* __restrict__ PKn,
                                                 __bf16* __restrict__ A2n, int nu, int umax) {
    int u = blockIdx.x * 4 + (threadIdx.x >> 6);
    if (u >= nu) return;
    int lane = threadIdx.x & 63;
    int g = lane >> 4, l16 = lane & 15;
    int off = off_all[u], n = off_all[u + 1] - off;
    if (n == 0) {
        if (lane < 16) {
            bf16x8 z = {};
            *(bf16x8*)(A1n + (size_t)u * D_ + l16 * 8) = z;
            *(bf16x8*)(PKn + (size_t)u * D_ + l16 * 8) = z;
            *(bf16x8*)(A2n + (size_t)u * D_ + l16 * 8) = z;
        }
        return;
    }
    float um8[8], li8[8], lu8[8];
    unpack8(((const bf16x8*)(um_t + (size_t)u * D_))[l16], um8);
    unpack8(((const bf16x8*)(li_t + (size_t)u * D_))[l16], li8);
    unpack8(((const bf16x8*)(lu_t + (size_t)u * D_))[l16], lu8);
    const __bf16* upv_row = upv + (size_t)u * umax;

    float s1 = 0.f, s2 = 0.f, a1[8] = {}, apk[8] = {}, a2[8] = {};
    for (int i = g; i < n; i += 8) {
        i32x2 ra = __builtin_nontemporal_load((const i32x2*)(u_list + (size_t)(off + i) * 2));
        bool hb = (i + 4) < n;
        i32x2 rb = __builtin_nontemporal_load((const i32x2*)(u_list + (size_t)(off + (hb ? i + 4 : i)) * 2));
        int itA = ra[0] & 0x3FFFF, r1A = (ra[0] >> 18) & 0x3F, r2A = (ra[0] >> 24) & 0x3F;
        int itB = rb[0] & 0x3FFFF, r1B = (rb[0] >> 18) & 0x3F, r2B = (rb[0] >> 24) & 0x3F;
        bf16x8 vieA = ((const bf16x8*)(ib_emb + (size_t)itA * D_))[l16];
        bf16x8 vpkA = ((const bf16x8*)(pKb + (size_t)r2A * D_))[l16];
        bf16x8 vieB = ((const bf16x8*)(ib_emb + (size_t)itB * D_))[l16];
        bf16x8 vpkB = ((const bf16x8*)(pKb + (size_t)r2B * D_))[l16];
        float fieA[8], fpkA[8], fieB[8], fpkB[8];
        unpack8(vieA, fieA); unpack8(vpkA, fpkA);
        unpack8(vieB, fieB); unpack8(vpkB, fpkB);
        float d1a = 0.f, d2a = 0.f, d3a = 0.f, d1b = 0.f, d2b = 0.f, d3b = 0.f;
#pragma unroll
        for (int j = 0; j < 8; j++) {
            d1a = fmaf(um8[j], fieA[j], d1a);
            d2a = fmaf(li8[j], fieA[j], d2a);
            d3a = fmaf(lu8[j], fieA[j], d3a);
            d1b = fmaf(um8[j], fieB[j], d1b);
            d2b = fmaf(li8[j], fieB[j], d2b);
            d3b = fmaf(lu8[j], fieB[j], d3b);
        }
#pragma unroll
        for (int d = 1; d < 16; d <<= 1) {
            d1a += __shfl_xor(d1a, d); d2a += __shfl_xor(d2a, d); d3a += __shfl_xor(d3a, d);
            d1b += __shfl_xor(d1b, d); d2b += __shfl_xor(d2b, d); d3b += __shfl_xor(d3b, d);
        }
        if (l16 == 0) {
            f32x4 recA;
            recA[0] = d1a; recA[1] = d3a;
            recA[2] = __int_as_float(u | (ra[0] & 0x3FFC0000)); recA[3] = 0.f;
            __builtin_nontemporal_store(recA, (f32x4*)(mb_rec + (size_t)ra[1] * 4));
            if (hb) {
                f32x4 recB;
                recB[0] = d1b; recB[1] = d3b;
                recB[2] = __int_as_float(u | (rb[0] & 0x3FFC0000)); recB[3] = 0.f;
                __builtin_nontemporal_store(recB, (f32x4*)(mb_rec + (size_t)rb[1] * 4));
            }
        }
        float w1a = __expf(d1a + bf2f(upv_row[r1A]));
        float w2a = __expf(d2a);
        float w1b = hb ? __expf(d1b + bf2f(upv_row[r1B])) : 0.f;
        float w2b = hb ? __expf(d2b) : 0.f;
        s1 += w1a + w1b; s2 += w2a + w2b;
#pragma unroll
        for (int j = 0; j < 8; j++) {
            a1[j]  = fmaf(w1a, fieA[j], fmaf(w1b, fieB[j], a1[j]));
            apk[j] = fmaf(w1a, fpkA[j], fmaf(w1b, fpkB[j], apk[j]));
            a2[j]  = fmaf(w2a, fieA[j], fmaf(w2b, fieB[j], a2[j]));
        }
    }
#pragma unroll
    for (int d = 16; d < 64; d <<= 1) {
        s1 += __shfl_xor(s1, d); s2 += __shfl_xor(s2, d);
#pragma unroll
        for (int j = 0; j < 8; j++) {
            a1[j]  += __shfl_xor(a1[j], d);
            apk[j] += __shfl_xor(apk[j], d);
            a2[j]  += __shfl_xor(a2[j], d);
        }
    }
    if (lane < 16) {
        float inv1 = 1.f / s1, inv2 = 1.f / s2;
        *(bf16x8*)(A1n + (size_t)u * D_ + l16 * 8) = pack8(a1, inv1);
        *(bf16x8*)(PKn + (size_t)u * D_ + l16 * 8) = pack8(apk, inv1);
        *(bf16x8*)(A2n + (size_t)u * D_ + l16 * 8) = pack8(a2, inv2);
    }
}

// ---------------- item pass: 2x unroll, single coalesced record stream ----------------
__global__ __launch_bounds__(256) void item_pass(const int* __restrict__ off_all,
                                                 const __bf16* __restrict__ ub_emb,
                                                 const __bf16* __restrict__ pVb,
                                                 const __bf16* __restrict__ ipk,
                                                 const float* __restrict__ mb_rec,
                                                 __bf16* __restrict__ B1n, __bf16* __restrict__ PVn,
                                                 __bf16* __restrict__ B2n, int nu, int ni, int imax, int E) {
    int it = blockIdx.x * 4 + (threadIdx.x >> 6);
    if (it >= ni) return;
    int lane = threadIdx.x & 63;
    int g = lane >> 4, l16 = lane & 15;
    int ioff = off_all[nu + it] - E, n = off_all[nu + it + 1] - E - ioff;
    if (n == 0) {
        if (lane < 16) {
            bf16x8 z = {};
            *(bf16x8*)(B1n + (size_t)it * D_ + l16 * 8) = z;
            *(bf16x8*)(PVn + (size_t)it * D_ + l16 * 8) = z;
            *(bf16x8*)(B2n + (size_t)it * D_ + l16 * 8) = z;
        }
        return;
    }
    const __bf16* ipk_row = ipk + (size_t)it * imax;

    float s1 = 0.f, s2 = 0.f, b1[8] = {}, bpv[8] = {}, b2[8] = {};
    for (int i = g; i < n; i += 8) {
        f32x4 ra = __builtin_nontemporal_load((const f32x4*)(mb_rec + (size_t)(ioff + i) * 4));
        bool hb = (i + 4) < n;
        f32x4 rb = __builtin_nontemporal_load((const f32x4*)(mb_rec + (size_t)(ioff + (hb ? i + 4 : i)) * 4));
        int pa = __float_as_int(ra[2]), pb = __float_as_int(rb[2]);
        int uA = pa & 0x3FFFF, r1A = (pa >> 18) & 0x3F, r2A = (pa >> 24) & 0x3F;
        int uB = pb & 0x3FFFF, r1B = (pb >> 18) & 0x3F, r2B = (pb >> 24) & 0x3F;
        bf16x8 vueA = ((const bf16x8*)(ub_emb + (size_t)uA * D_))[l16];
        bf16x8 vpvA = ((const bf16x8*)(pVb + (size_t)r1A * D_))[l16];
        bf16x8 vueB = ((const bf16x8*)(ub_emb + (size_t)uB * D_))[l16];
        bf16x8 vpvB = ((const bf16x8*)(pVb + (size_t)r1B * D_))[l16];
        float fueA[8], fpvA[8], fueB[8], fpvB[8];
        unpack8(vueA, fueA); unpack8(vpvA, fpvA);
        unpack8(vueB, fueB); unpack8(vpvB, fpvB);
        float w1a = __expf(ra[0] + bf2f(ipk_row[r2A]));
        float w2a = __expf(ra[1]);
        float w1b = hb ? __expf(rb[0] + bf2f(ipk_row[r2B])) : 0.f;
        float w2b = hb ? __expf(rb[1]) : 0.f;
        s1 += w1a + w1b; s2 += w2a + w2b;
#pragma unroll
        for (int j = 0; j < 8; j++) {
            b1[j]  = fmaf(w1a, fueA[j], fmaf(w1b, fueB[j], b1[j]));
            bpv[j] = fmaf(w1a, fpvA[j], fmaf(w1b, fpvB[j], bpv[j]));
            b2[j]  = fmaf(w2a, fueA[j], fmaf(w2b, fueB[j], b2[j]));
        }
    }
#pragma unroll
    for (int d = 16; d < 64; d <<= 1) {
        s1 += __shfl_xor(s1, d); s2 += __shfl_xor(s2, d);
#pragma unroll
        for (int j = 0; j < 8; j++) {
            b1[j]  += __shfl_xor(b1[j], d);
            bpv[j] += __shfl_xor(bpv[j], d);
            b2[j]  += __shfl_xor(b2[j], d);
        }
    }
    if (lane < 16) {
        float inv1 = 1.f / s1, inv2 = 1.f / s2;
        *(bf16x8*)(B1n + (size_t)it * D_ + l16 * 8) = pack8(b1, inv1);
        *(bf16x8*)(PVn + (size_t)it * D_ + l16 * 8) = pack8(bpv, inv1);
        *(bf16x8*)(B2n + (size_t)it * D_ + l16 * 8) = pack8(b2, inv2);
    }
}

// ---------------- finish GEMM (4 configs via blockIdx.y), swapped-operand direct-store epilogue ----------------
struct FinArgs { const __bf16* A; const __bf16* W; const __bf16* side; const int* offseg; float* out; int rows; };
struct Fin4 { FinArgs f[4]; };
__global__ __launch_bounds__(256) void finish4(Fin4 fa) {
    FinArgs q = fa.f[blockIdx.y];
    if (blockIdx.x * 256 >= (unsigned)q.rows) return;
    __shared__ __bf16 sW[128][136];
    int t = threadIdx.x;
#pragma unroll
    for (int it = 0; it < 8; it++) {
        int slot = it * 256 + t;
        int r = slot >> 4, c16 = (slot & 15) * 8;
        bf16x8 v = *(const bf16x8*)(q.W + (size_t)r * D_ + c16);
        *(bf16x8*)(&sW[r][c16]) = v;
    }
    __syncthreads();
    int lane = t & 63, wave = t >> 6;
    int l16 = lane & 15, kh = lane >> 4;

    for (int tt = 0; tt < 4; tt++) {
        int rowblk = blockIdx.x * 256 + (tt * 4 + wave) * 16;
        if (rowblk >= q.rows) break;
        int ar = rowblk + l16;
        bool rok = ar < q.rows;
        int arc = rok ? ar : q.rows - 1;
        const __bf16* rA = q.A + (size_t)arc * D_;
        bf16x8 b0 = *(const bf16x8*)(rA + kh * 8);
        bf16x8 b1 = *(const bf16x8*)(rA + 32 + kh * 8);
        bf16x8 b2 = *(const bf16x8*)(rA + 64 + kh * 8);
        bf16x8 b3 = *(const bf16x8*)(rA + 96 + kh * 8);
        float addv = 0.f;
        if (!q.side && rok) addv = (q.offseg[ar + 1] - q.offseg[ar]) > 0 ? 1.f : 0.f;
#pragma unroll
        for (int cc = 0; cc < 8; cc++) {
            int wr = cc * 16 + l16;
            f32x4 acc = {};
            acc = __builtin_amdgcn_mfma_f32_16x16x32_bf16(*(const bf16x8*)(&sW[wr][kh * 8]), b0, acc, 0, 0, 0);
            acc = __builtin_amdgcn_mfma_f32_16x16x32_bf16(*(const bf16x8*)(&sW[wr][32 + kh * 8]), b1, acc, 0, 0, 0);
            acc = __builtin_amdgcn_mfma_f32_16x16x32_bf16(*(const bf16x8*)(&sW[wr][64 + kh * 8]), b2, acc, 0, 0, 0);
            acc = __builtin_amdgcn_mfma_f32_16x16x32_bf16(*(const bf16x8*)(&sW[wr][96 + kh * 8]), b3, acc, 0, 0, 0);
            if (rok) {
                int col = cc * 16 + kh * 4;
                float4 v = make_float4(acc[0], acc[1], acc[2], acc[3]);
                if (q.side) {
                    ushort4 sv = *(const ushort4*)((const unsigned short*)q.side + (size_t)ar * D_ + col);
                    v.x += __uint_as_float((uint32_t)sv.x << 16);
                    v.y += __uint_as_float((uint32_t)sv.y << 16);
                    v.z += __uint_as_float((uint32_t)sv.z << 16);
                    v.w += __uint_as_float((uint32_t)sv.w << 16);
                } else {
                    v.x += addv; v.y += addv; v.z += addv; v.w += addv;
                }
                *(float4*)(q.out + (size_t)ar * D_ + col) = v;
            }
        }
    }
}

extern "C" void kernel_launch(void* const* d_in, const int* in_sizes, int n_in,
                              void* d_out, int out_size, void* d_ws, size_t ws_size,
                              hipStream_t stream) {
    (void)n_in; (void)out_size; (void)ws_size;
    const float* u_emb = (const float*)d_in[0];
    const float* i_emb = (const float*)d_in[1];
    const int* edge_u = (const int*)d_in[2];
    const int* edge_i = (const int*)d_in[3];
    const int* rui = (const int*)d_in[4];
    const int* riu = (const int*)d_in[5];
    const int* last_u_items = (const int*)d_in[6];
    const int* last_i_users = (const int*)d_in[7];
    const float* W1  = (const float*)d_in[8];
    const float* W2  = (const float*)d_in[9];
    const float* W1b = (const float*)d_in[10];
    const float* W2b = (const float*)d_in[11];
    const float* W3  = (const float*)d_in[12];
    const float* W4  = (const float*)d_in[13];
    const float* pV  = (const float*)d_in[14];
    const float* pK  = (const float*)d_in[15];
    const float* last_user_table = (const float*)d_in[16];
    const float* last_item_table = (const float*)d_in[17];

    const int NU = in_sizes[0] / D_;
    const int NI = in_sizes[1] / D_;
    const int E  = in_sizes[2];
    const int UMAXr = in_sizes[14] / D_;
    const int IMAXr = in_sizes[15] / D_;
    const int NSEG = NU + NI;

    size_t cur = 0;
    auto alloc = [&](size_t bytes) -> void* {
        void* p = (char*)d_ws + cur;
        cur += (bytes + 255) & ~(size_t)255;
        return p;
    };

    __bf16* Wb4   = (__bf16*)alloc(4 * 16384 * 2);
    __bf16* M2t   = (__bf16*)alloc(16384 * 2);
    __bf16* M3t   = (__bf16*)alloc(16384 * 2);
    __bf16* M4t   = (__bf16*)alloc(16384 * 2);
    __bf16* pVW2  = (__bf16*)alloc((size_t)UMAXr * D_ * 2);
    __bf16* pKW1  = (__bf16*)alloc((size_t)IMAXr * D_ * 2);
    __bf16* pVb   = (__bf16*)alloc((size_t)UMAXr * D_ * 2);
    __bf16* pKb   = (__bf16*)alloc((size_t)IMAXr * D_ * 2);
    __bf16* ub_emb = (__bf16*)alloc((size_t)NU * D_ * 2);
    __bf16* ib_emb = (__bf16*)alloc((size_t)NI * D_ * 2);
    __bf16* um_t  = (__bf16*)alloc((size_t)NU * D_ * 2);
    __bf16* li_t  = (__bf16*)alloc((size_t)NU * D_ * 2);
    __bf16* lu_t  = (__bf16*)alloc((size_t)NU * D_ * 2);
    __bf16* upv   = (__bf16*)alloc((size_t)NU * UMAXr * 2);
    __bf16* ipk   = (__bf16*)alloc((size_t)NI * IMAXr * 2);
    __bf16* A1n   = (__bf16*)alloc((size_t)NU * D_ * 2);
    __bf16* PKn   = (__bf16*)alloc((size_t)NU * D_ * 2);
    __bf16* A2n   = (__bf16*)alloc((size_t)NU * D_ * 2);
    __bf16* B1n   = (__bf16*)alloc((size_t)NI * D_ * 2);
    __bf16* PVn   = (__bf16*)alloc((size_t)NI * D_ * 2);
    __bf16* B2n   = (__bf16*)alloc((size_t)NI * D_ * 2);
    float* mb_rec = (float*)alloc((size_t)E * 16);
    int* u_list   = (int*)alloc((size_t)E * 8);
    int* cnt_all  = (int*)alloc((size_t)NSEG * 4);
    int* off_all  = (int*)alloc((size_t)(NSEG + 1) * 4);
    int* pos_all  = (int*)alloc((size_t)NSEG * 4);
    int* parts    = (int*)alloc(1024 * 4);

    float* out = (float*)d_out;
    float* hLu = out;
    float* hSu = out + (size_t)NU * D_;
    float* hLi = out + (size_t)2 * NU * D_;
    float* hSi = out + (size_t)2 * NU * D_ + (size_t)NI * D_;

    // zero counters first (hist merged into prep_all)
    hipMemsetAsync(cnt_all, 0, (size_t)NSEG * 4, stream);

    // merged prep: weight/p casts + emb casts + histogram
    int npv = UMAXr * D_, npk = IMAXr * D_;
    size_t nue = (size_t)NU * D_, nie = (size_t)NI * D_;
    PrepArgs pa;
    pa.w.p[0] = W1; pa.w.p[1] = W2; pa.w.p[2] = W1b; pa.w.p[3] = W2b;
    pa.pV = pV; pa.pK = pK; pa.outW = Wb4; pa.pVb = pVb; pa.pKb = pKb; pa.npv = npv; pa.npk = npk;
    pa.u_emb = u_emb; pa.i_emb = i_emb; pa.ub = ub_emb; pa.ib = ib_emb; pa.nue = nue; pa.nie = nie;
    pa.eu = edge_u; pa.ei = edge_i; pa.cnt_all = cnt_all; pa.nu = NU; pa.E = E;
    pa.wb_blocks = (4 * 16384 + npv + npk + 255) / 256;
    pa.eb_blocks = (int)(((nue + nie) / 4 + 255) / 256);
    int hb_blocks = (E + 255) / 256;
    prep_all<<<pa.wb_blocks + pa.eb_blocks + hb_blocks, 256, 0, stream>>>(pa);

    prep_mats<<<128 + (UMAXr > IMAXr ? UMAXr : IMAXr), 128, 0, stream>>>(W1, W2, W3, W4, pV, pK,
                                                                         M2t, M3t, M4t, pVW2, pKW1, UMAXr, IMAXr);

    // CSR scan chain
    int nb = (NSEG + SCAN_TILE - 1) / SCAN_TILE;
    scan_phaseA<<<nb, 256, 0, stream>>>(cnt_all, parts, NSEG);
    scan_phaseB<<<1, 1024, 0, stream>>>(parts, nb, off_all, NSEG);
    scan_phaseC<<<nb, 256, 0, stream>>>(cnt_all, parts, off_all, pos_all, NSEG);
    scatter2<<<(E + 255) / 256, 256, 0, stream>>>(edge_u, edge_i, rui, riu, pos_all, u_list, NU, E);

    // merged: user vectors + pvk GEMMs (one launch)
    int gu = (NU + 63) / 64, gi = (NI + 63) / 64;
    int gmax = gu > gi ? gu : gi;
    VecsPvk vp;
    vp.u_emb = u_emb; vp.lit_tab = last_item_table; vp.g_li = last_u_items;
    vp.lut_tab = last_user_table; vp.g_lu = last_i_users;
    vp.M2t = M2t; vp.M3t = M3t; vp.M4t = M4t;
    vp.um_t = um_t; vp.li_t = li_t; vp.lu_t = lu_t; vp.nu = NU;
    vp.a[0] = {ub_emb, pVW2, upv, NU, UMAXr};
    vp.a[1] = {ib_emb, pKW1, ipk, NI, IMAXr};
    vecs_pvk<<<dim3(gmax, 3), 256, 0, stream>>>(vp);

    // edge passes
    user_pass<<<(NU + 3) / 4, 256, 0, stream>>>(off_all, u_list, ib_emb, um_t, li_t, lu_t,
                                                pKb, upv, mb_rec, A1n, PKn, A2n, NU, UMAXr);
    item_pass<<<(NI + 3) / 4, 256, 0, stream>>>(off_all, ub_emb, pVb, ipk, mb_rec,
                                                B1n, PVn, B2n, NU, NI, IMAXr, E);

    // finish projections (one launch, 4 configs)
    int fu = (NU + 255) / 256, fi = (NI + 255) / 256;
    Fin4 fa;
    fa.f[0] = {A1n, Wb4 + 2 * 16384, PKn, nullptr, hLu, NU};
    fa.f[1] = {A2n, Wb4 + 0 * 16384, nullptr, off_all, hSu, NU};
    fa.f[2] = {B1n, Wb4 + 3 * 16384, PVn, nullptr, hLi, NI};
    fa.f[3] = {B2n, Wb4 + 1 * 16384, nullptr, off_all + NU, hSi, NI};
    finish4<<<dim3((fu > fi ? fu : fi), 4), 256, 0, stream>>>(fa);
}

// Round 19
// 467.988 us; speedup vs baseline: 1.1007x; 1.0177x over previous
//
#include <hip/hip_runtime.h>
#include <hip/hip_bf16.h>
#include <math.h>

#define D_ 128
#define INV_SQRT_D 0.08838834764831845f
#define SCAN_CH 16
#define SCAN_TILE (256 * SCAN_CH)

typedef __bf16 bf16x8 __attribute__((ext_vector_type(8)));
typedef float f32x4 __attribute__((ext_vector_type(4)));
typedef int i32x2 __attribute__((ext_vector_type(2)));

struct W4p { const float* p[4]; };

__device__ __forceinline__ void unpack8(bf16x8 v, float* f) {
    const uint32_t* u = (const uint32_t*)&v;
#pragma unroll
    for (int i = 0; i < 4; i++) {
        uint32_t w = u[i];
        f[2 * i]     = __uint_as_float(w << 16);
        f[2 * i + 1] = __uint_as_float(w & 0xffff0000u);
    }
}

__device__ __forceinline__ bf16x8 pack8(const float* f, float s) {
    bf16x8 r;
#pragma unroll
    for (int j = 0; j < 8; j++) r[j] = (__bf16)(f[j] * s);
    return r;
}

__device__ __forceinline__ float bf2f(__bf16 v) {
    return __uint_as_float((uint32_t)(*(unsigned short*)&v) << 16);
}

// ---------------- merged prep: weight/p-table casts + emb casts + edge histogram ----------------
struct PrepArgs {
    W4p w; const float* pV; const float* pK;
    __bf16* outW; __bf16* pVb; __bf16* pKb; int npv; int npk;
    const float* u_emb; const float* i_emb; __bf16* ub; __bf16* ib;
    size_t nue; size_t nie;
    const int* eu; const int* ei; int* cnt_all; int nu; int E;
    int wb_blocks; int eb_blocks;
};
__global__ __launch_bounds__(256) void prep_all(PrepArgs a) {
    int b = blockIdx.x;
    if (b < a.wb_blocks) {
        int idx = b * 256 + threadIdx.x;
        if (idx < 4 * 16384) {
            a.outW[idx] = (__bf16)a.w.p[idx >> 14][idx & 16383];
        } else if (idx - 4 * 16384 < a.npv) {
            int j = idx - 4 * 16384;
            a.pVb[j] = (__bf16)a.pV[j];
        } else if (idx - 4 * 16384 - a.npv < a.npk) {
            int j = idx - 4 * 16384 - a.npv;
            a.pKb[j] = (__bf16)a.pK[j];
        }
    } else if (b < a.wb_blocks + a.eb_blocks) {
        size_t idx4 = ((size_t)(b - a.wb_blocks) * 256 + threadIdx.x) * 4;
        if (idx4 < a.nue) {
            float4 v = *(const float4*)(a.u_emb + idx4);
            a.ub[idx4] = (__bf16)v.x; a.ub[idx4+1] = (__bf16)v.y; a.ub[idx4+2] = (__bf16)v.z; a.ub[idx4+3] = (__bf16)v.w;
        } else if (idx4 < a.nue + a.nie) {
            size_t j = idx4 - a.nue;
            float4 v = *(const float4*)(a.i_emb + j);
            a.ib[j] = (__bf16)v.x; a.ib[j+1] = (__bf16)v.y; a.ib[j+2] = (__bf16)v.z; a.ib[j+3] = (__bf16)v.w;
        }
    } else {
        int e = (b - a.wb_blocks - a.eb_blocks) * 256 + threadIdx.x;
        if (e < a.E) {
            atomicAdd(&a.cnt_all[a.eu[e]], 1);
            atomicAdd(&a.cnt_all[a.nu + a.ei[e]], 1);
        }
    }
}

// ---------------- combined-matrix prep ----------------
__global__ __launch_bounds__(128) void prep_mats(const float* __restrict__ W1, const float* __restrict__ W2,
                                                 const float* __restrict__ W3, const float* __restrict__ W4,
                                                 const float* __restrict__ pV, const float* __restrict__ pK,
                                                 __bf16* __restrict__ M2t, __bf16* __restrict__ M3t,
                                                 __bf16* __restrict__ M4t,
                                                 __bf16* __restrict__ pVW2, __bf16* __restrict__ pKW1,
                                                 int umax, int imax) {
    __shared__ float sh[256];
    int b = blockIdx.x, t = threadIdx.x;
    if (b < 128) {
        sh[t] = W1[t * 128 + b];
        __syncthreads();
        float m2 = 0.f, m3 = 0.f, m4 = 0.f;
        for (int k = 0; k < 128; k++) {
            float w = sh[k];
            m2 = fmaf(w, W2[k * 128 + t], m2);
            m3 = fmaf(w, W3[k * 128 + t], m3);
            m4 = fmaf(w, W4[k * 128 + t], m4);
        }
        M2t[b * 128 + t] = (__bf16)(m2 * INV_SQRT_D);
        M3t[b * 128 + t] = (__bf16)(m3 * INV_SQRT_D);
        M4t[b * 128 + t] = (__bf16)(m4 * INV_SQRT_D);
    } else {
        int r = b - 128;
        if (r < umax) sh[t] = pV[r * 128 + t];
        if (r < imax) sh[128 + t] = pK[r * 128 + t];
        __syncthreads();
        float q = 0.f, qk = 0.f;
        for (int a = 0; a < 128; a++) {
            if (r < umax) q  = fmaf(sh[a], W2[a * 128 + t], q);
            if (r < imax) qk = fmaf(sh[128 + a], W1[a * 128 + t], qk);
        }
        if (r < umax) pVW2[r * 128 + t] = (__bf16)(q * INV_SQRT_D);
        if (r < imax) pKW1[r * 128 + t] = (__bf16)(qk * INV_SQRT_D);
    }
}

// ---------------- merged: user vectors (y=0) + pvk GEMMs (y=1,2) ----------------
struct PvkA { const __bf16* X; const __bf16* P; __bf16* Y; int rows; int ncols; };
struct VecsPvk {
    const float* u_emb; const float* lit_tab; const int* g_li;
    const float* lut_tab; const int* g_lu;
    const __bf16* M2t; const __bf16* M3t; const __bf16* M4t;
    __bf16* um_t; __bf16* li_t; __bf16* lu_t; int nu;
    PvkA a[2];
};
__global__ __launch_bounds__(256) void vecs_pvk(VecsPvk p) {
    int lane = threadIdx.x & 63;
    int wave = threadIdx.x >> 6;
    int row0 = blockIdx.x * 64 + wave * 16;
    int l16 = lane & 15, kh = lane >> 4;
    if (blockIdx.y == 0) {
        int rows = p.nu;
        if (row0 >= rows) return;
        int ar = row0 + l16;
        int arc = ar < rows ? ar : rows - 1;
        const float* rA = p.u_emb + (size_t)arc * D_;
        const float* rB = p.lit_tab + (size_t)p.g_li[arc] * D_;
        const float* rC = p.lut_tab + (size_t)p.g_lu[arc] * D_;

        f32x4 aA[8] = {}, aB[8] = {}, aC[8] = {};
#pragma unroll
        for (int k0 = 0; k0 < D_; k0 += 32) {
            int kk = k0 + kh * 8;
            float4 a0 = *(const float4*)(rA + kk), a1 = *(const float4*)(rA + kk + 4);
            float4 b0 = *(const float4*)(rB + kk), b1 = *(const float4*)(rB + kk + 4);
            float4 c0 = *(const float4*)(rC + kk), c1 = *(const float4*)(rC + kk + 4);
            bf16x8 fA, fB, fC;
            fA[0]=(__bf16)a0.x; fA[1]=(__bf16)a0.y; fA[2]=(__bf16)a0.z; fA[3]=(__bf16)a0.w;
            fA[4]=(__bf16)a1.x; fA[5]=(__bf16)a1.y; fA[6]=(__bf16)a1.z; fA[7]=(__bf16)a1.w;
            fB[0]=(__bf16)b0.x; fB[1]=(__bf16)b0.y; fB[2]=(__bf16)b0.z; fB[3]=(__bf16)b0.w;
            fB[4]=(__bf16)b1.x; fB[5]=(__bf16)b1.y; fB[6]=(__bf16)b1.z; fB[7]=(__bf16)b1.w;
            fC[0]=(__bf16)c0.x; fC[1]=(__bf16)c0.y; fC[2]=(__bf16)c0.z; fC[3]=(__bf16)c0.w;
            fC[4]=(__bf16)c1.x; fC[5]=(__bf16)c1.y; fC[6]=(__bf16)c1.z; fC[7]=(__bf16)c1.w;
#pragma unroll
            for (int cb = 0; cb < 8; cb++) {
                bf16x8 w2 = *(const bf16x8*)(p.M2t + (size_t)(cb * 16 + l16) * D_ + kk);
                aA[cb] = __builtin_amdgcn_mfma_f32_16x16x32_bf16(fA, w2, aA[cb], 0, 0, 0);
                bf16x8 w3 = *(const bf16x8*)(p.M3t + (size_t)(cb * 16 + l16) * D_ + kk);
                aB[cb] = __builtin_amdgcn_mfma_f32_16x16x32_bf16(fB, w3, aB[cb], 0, 0, 0);
                bf16x8 w4 = *(const bf16x8*)(p.M4t + (size_t)(cb * 16 + l16) * D_ + kk);
                aC[cb] = __builtin_amdgcn_mfma_f32_16x16x32_bf16(fC, w4, aC[cb], 0, 0, 0);
            }
        }
#pragma unroll
        for (int cb = 0; cb < 8; cb++) {
#pragma unroll
            for (int j = 0; j < 4; j++) {
                int r = row0 + kh * 4 + j;
                if (r < rows) {
                    p.um_t[(size_t)r * D_ + cb * 16 + l16] = (__bf16)aA[cb][j];
                    p.li_t[(size_t)r * D_ + cb * 16 + l16] = (__bf16)aB[cb][j];
                    p.lu_t[(size_t)r * D_ + cb * 16 + l16] = (__bf16)aC[cb][j];
                }
            }
        }
    } else {
        PvkA q = p.a[blockIdx.y - 1];
        if (row0 >= q.rows) return;
        int ar = row0 + l16;
        int arc = ar < q.rows ? ar : q.rows - 1;
        const __bf16* arow = q.X + (size_t)arc * D_;

        f32x4 acc[4] = {};
#pragma unroll
        for (int k0 = 0; k0 < D_; k0 += 32) {
            int kk = k0 + kh * 8;
            bf16x8 af = *(const bf16x8*)(arow + kk);
#pragma unroll
            for (int cb = 0; cb < 4; cb++) {
                int br = cb * 16 + l16;
                if (br >= q.ncols) br = q.ncols - 1;
                bf16x8 bf = *(const bf16x8*)(q.P + (size_t)br * D_ + kk);
                acc[cb] = __builtin_amdgcn_mfma_f32_16x16x32_bf16(af, bf, acc[cb], 0, 0, 0);
            }
        }
#pragma unroll
        for (int cb = 0; cb < 4; cb++) {
            int col = cb * 16 + l16;
            if (col >= q.ncols) continue;
#pragma unroll
            for (int j = 0; j < 4; j++) {
                int r = row0 + kh * 4 + j;
                if (r < q.rows) q.Y[(size_t)r * q.ncols + col] = (__bf16)acc[cb][j];
            }
        }
    }
}

// ---------------- scans ----------------
__global__ __launch_bounds__(256) void scan_phaseA(const int* __restrict__ cnt, int* __restrict__ part, int n) {
    __shared__ int wsum[4];
    int t = threadIdx.x, lane = t & 63, w = t >> 6;
    int i0 = blockIdx.x * SCAN_TILE + t * SCAN_CH;
    int tot = 0;
#pragma unroll
    for (int j = 0; j < SCAN_CH; j++) tot += (i0 + j < n) ? cnt[i0 + j] : 0;
#pragma unroll
    for (int d = 32; d; d >>= 1) tot += __shfl_xor(tot, d);
    if (lane == 0) wsum[w] = tot;
    __syncthreads();
    if (t == 0) part[blockIdx.x] = wsum[0] + wsum[1] + wsum[2] + wsum[3];
}

__global__ __launch_bounds__(1024) void scan_phaseB(int* __restrict__ part, int nb,
                                                    int* __restrict__ off, int n) {
    __shared__ int wsum[16];
    int t = threadIdx.x, lane = t & 63, w = t >> 6;
    int v = (t < nb) ? part[t] : 0;
    int x = v;
#pragma unroll
    for (int d = 1; d < 64; d <<= 1) {
        int y = __shfl_up(x, d);
        if (lane >= d) x += y;
    }
    if (lane == 63) wsum[w] = x;
    __syncthreads();
    int wbase = 0;
    for (int ww = 0; ww < w; ww++) wbase += wsum[ww];
    if (t < nb) part[t] = wbase + x - v;
    if (t == 1023) off[n] = wbase + x;
}

__global__ __launch_bounds__(256) void scan_phaseC(const int* __restrict__ cnt, const int* __restrict__ part,
                                                   int* __restrict__ off, int* __restrict__ pos, int n) {
    __shared__ int wsum[4];
    int t = threadIdx.x, lane = t & 63, w = t >> 6;
    int i0 = blockIdx.x * SCAN_TILE + t * SCAN_CH;
    int loc[SCAN_CH];
    int tot = 0;
#pragma unroll
    for (int j = 0; j < SCAN_CH; j++) {
        int v = (i0 + j < n) ? cnt[i0 + j] : 0;
        loc[j] = tot; tot += v;
    }
    int x = tot;
#pragma unroll
    for (int d = 1; d < 64; d <<= 1) {
        int y = __shfl_up(x, d);
        if (lane >= d) x += y;
    }
    if (lane == 63) wsum[w] = x;
    __syncthreads();
    int wbase = 0;
    for (int ww = 0; ww < w; ww++) wbase += wsum[ww];
    int excl = part[blockIdx.x] + wbase + x - tot;
#pragma unroll
    for (int j = 0; j < SCAN_CH; j++) {
        if (i0 + j < n) { off[i0 + j] = excl + loc[j]; pos[i0 + j] = excl + loc[j]; }
    }
}

// ---------------- scatter (standalone, low-VGPR, high occupancy) ----------------
__global__ __launch_bounds__(256) void scatter2(const int* __restrict__ eu, const int* __restrict__ ei,
                                                const int* __restrict__ rui, const int* __restrict__ riu,
                                                int* __restrict__ pos_all, int* __restrict__ u_list,
                                                int nu, int E) {
    int e = blockIdx.x * 256 + threadIdx.x;
    if (e < E) {
        int u = eu[e], it = ei[e], r1 = rui[e], r2 = riu[e];
        int rbits = (r1 << 18) | (r2 << 24);
        int pi = atomicAdd(&pos_all[nu + it], 1) - E;
        int pu = atomicAdd(&pos_all[u], 1);
        i32x2 rec;
        rec[0] = it | rbits;
        rec[1] = pi;
        __builtin_nontemporal_store(rec, (i32x2*)(u_list + (size_t)pu * 2));
    }
}

// ---------------- user pass: 2x unroll ----------------
__global__ __launch_bounds__(256) void user_pass(const int* __restrict__ off_all, const int* __restrict__ u_list,
                                                 const __bf16* __restrict__ ib_emb,
                                                 const __bf16* __restrict__ um_t,
                                                 const __bf16* __restrict__ li_t,
                                                 const __bf16* __restrict__ lu_t,
                                                 const __bf16* __restrict__ pKb,
                                                 const __bf16* __restrict__ upv,
                                                 float* __restrict__ mb_rec,
                                                 __bf16* __restrict__ A1n, __bf16* __restrict__ PKn,
                                                 __bf16* __restrict__ A2n, int nu, int umax) {
    int u = blockIdx.x * 4 + (threadIdx.x >> 6);
    if (u >= nu) return;
    int lane = threadIdx.x & 63;
    int g = lane >> 4, l16 = lane & 15;
    int off = off_all[u], n = off_all[u + 1] - off;
    if (n == 0) {
        if (lane < 16) {
            bf16x8 z = {};
            *(bf16x8*)(A1n + (size_t)u * D_ + l16 * 8) = z;
            *(bf16x8*)(PKn + (size_t)u * D_ + l16 * 8) = z;
            *(bf16x8*)(A2n + (size_t)u * D_ + l16 * 8) = z;
        }
        return;
    }
    float um8[8], li8[8], lu8[8];
    unpack8(((const bf16x8*)(um_t + (size_t)u * D_))[l16], um8);
    unpack8(((const bf16x8*)(li_t + (size_t)u * D_))[l16], li8);
    unpack8(((const bf16x8*)(lu_t + (size_t)u * D_))[l16], lu8);
    const __bf16* upv_row = upv + (size_t)u * umax;

    float s1 = 0.f, s2 = 0.f, a1[8] = {}, apk[8] = {}, a2[8] = {};
    for (int i = g; i < n; i += 8) {
        i32x2 ra = *(const i32x2*)(u_list + (size_t)(off + i) * 2);
        bool hb = (i + 4) < n;
        i32x2 rb = *(const i32x2*)(u_list + (size_t)(off + (hb ? i + 4 : i)) * 2);
        int itA = ra[0] & 0x3FFFF, r1A = (ra[0] >> 18) & 0x3F, r2A = (ra[0] >> 24) & 0x3F;
        int itB = rb[0] & 0x3FFFF, r1B = (rb[0] >> 18) & 0x3F, r2B = (rb[0] >> 24) & 0x3F;
        bf16x8 vieA = ((const bf16x8*)(ib_emb + (size_t)itA * D_))[l16];
        bf16x8 vpkA = ((const bf16x8*)(pKb + (size_t)r2A * D_))[l16];
        bf16x8 vieB = ((const bf16x8*)(ib_emb + (size_t)itB * D_))[l16];
        bf16x8 vpkB = ((const bf16x8*)(pKb + (size_t)r2B * D_))[l16];
        float fieA[8], fpkA[8], fieB[8], fpkB[8];
        unpack8(vieA, fieA); unpack8(vpkA, fpkA);
        unpack8(vieB, fieB); unpack8(vpkB, fpkB);
        float d1a = 0.f, d2a = 0.f, d3a = 0.f, d1b = 0.f, d2b = 0.f, d3b = 0.f;
#pragma unroll
        for (int j = 0; j < 8; j++) {
            d1a = fmaf(um8[j], fieA[j], d1a);
            d2a = fmaf(li8[j], fieA[j], d2a);
            d3a = fmaf(lu8[j], fieA[j], d3a);
            d1b = fmaf(um8[j], fieB[j], d1b);
            d2b = fmaf(li8[j], fieB[j], d2b);
            d3b = fmaf(lu8[j], fieB[j], d3b);
        }
#pragma unroll
        for (int d = 1; d < 16; d <<= 1) {
            d1a += __shfl_xor(d1a, d); d2a += __shfl_xor(d2a, d); d3a += __shfl_xor(d3a, d);
            d1b += __shfl_xor(d1b, d); d2b += __shfl_xor(d2b, d); d3b += __shfl_xor(d3b, d);
        }
        if (l16 == 0) {
            f32x4 recA;
            recA[0] = d1a; recA[1] = d3a;
            recA[2] = __int_as_float(u | (ra[0] & 0x3FFC0000)); recA[3] = 0.f;
            __builtin_nontemporal_store(recA, (f32x4*)(mb_rec + (size_t)ra[1] * 4));
            if (hb) {
                f32x4 recB;
                recB[0] = d1b; recB[1] = d3b;
                recB[2] = __int_as_float(u | (rb[0] & 0x3FFC0000)); recB[3] = 0.f;
                __builtin_nontemporal_store(recB, (f32x4*)(mb_rec + (size_t)rb[1] * 4));
            }
        }
        float w1a = __expf(d1a + bf2f(upv_row[r1A]));
        float w2a = __expf(d2a);
        float w1b = hb ? __expf(d1b + bf2f(upv_row[r1B])) : 0.f;
        float w2b = hb ? __expf(d2b) : 0.f;
        s1 += w1a + w1b; s2 += w2a + w2b;
#pragma unroll
        for (int j = 0; j < 8; j++) {
            a1[j]  = fmaf(w1a, fieA[j], fmaf(w1b, fieB[j], a1[j]));
            apk[j] = fmaf(w1a, fpkA[j], fmaf(w1b, fpkB[j], apk[j]));
            a2[j]  = fmaf(w2a, fieA[j], fmaf(w2b, fieB[j], a2[j]));
        }
    }
#pragma unroll
    for (int d = 16; d < 64; d <<= 1) {
        s1 += __shfl_xor(s1, d); s2 += __shfl_xor(s2, d);
#pragma unroll
        for (int j = 0; j < 8; j++) {
            a1[j]  += __shfl_xor(a1[j], d);
            apk[j] += __shfl_xor(apk[j], d);
            a2[j]  += __shfl_xor(a2[j], d);
        }
    }
    if (lane < 16) {
        float inv1 = 1.f / s1, inv2 = 1.f / s2;
        *(bf16x8*)(A1n + (size_t)u * D_ + l16 * 8) = pack8(a1, inv1);
        *(bf16x8*)(PKn + (size_t)u * D_ + l16 * 8) = pack8(apk, inv1);
        *(bf16x8*)(A2n + (size_t)u * D_ + l16 * 8) = pack8(a2, inv2);
    }
}

// ---------------- item pass: 2x unroll, single coalesced record stream ----------------
__global__ __launch_bounds__(256) void item_pass(const int* __restrict__ off_all,
                                                 const __bf16* __restrict__ ub_emb,
                                                 const __bf16* __restrict__ pVb,
                                                 const __bf16* __restrict__ ipk,
                                                 const float4* __restrict__ mb_rec,
                                                 __bf16* __restrict__ B1n, __bf16* __restrict__ PVn,
                                                 __bf16* __restrict__ B2n, int nu, int ni, int imax, int E) {
    int it = blockIdx.x * 4 + (threadIdx.x >> 6);
    if (it >= ni) return;
    int lane = threadIdx.x & 63;
    int g = lane >> 4, l16 = lane & 15;
    int ioff = off_all[nu + it] - E, n = off_all[nu + it + 1] - E - ioff;
    if (n == 0) {
        if (lane < 16) {
            bf16x8 z = {};
            *(bf16x8*)(B1n + (size_t)it * D_ + l16 * 8) = z;
            *(bf16x8*)(PVn + (size_t)it * D_ + l16 * 8) = z;
            *(bf16x8*)(B2n + (size_t)it * D_ + l16 * 8) = z;
        }
        return;
    }
    const __bf16* ipk_row = ipk + (size_t)it * imax;

    float s1 = 0.f, s2 = 0.f, b1[8] = {}, bpv[8] = {}, b2[8] = {};
    for (int i = g; i < n; i += 8) {
        float4 ra = mb_rec[ioff + i];
        bool hb = (i + 4) < n;
        float4 rb = mb_rec[ioff + (hb ? i + 4 : i)];
        int pa = __float_as_int(ra.z), pb = __float_as_int(rb.z);
        int uA = pa & 0x3FFFF, r1A = (pa >> 18) & 0x3F, r2A = (pa >> 24) & 0x3F;
        int uB = pb & 0x3FFFF, r1B = (pb >> 18) & 0x3F, r2B = (pb >> 24) & 0x3F;
        bf16x8 vueA = ((const bf16x8*)(ub_emb + (size_t)uA * D_))[l16];
        bf16x8 vpvA = ((const bf16x8*)(pVb + (size_t)r1A * D_))[l16];
        bf16x8 vueB = ((const bf16x8*)(ub_emb + (size_t)uB * D_))[l16];
        bf16x8 vpvB = ((const bf16x8*)(pVb + (size_t)r1B * D_))[l16];
        float fueA[8], fpvA[8], fueB[8], fpvB[8];
        unpack8(vueA, fueA); unpack8(vpvA, fpvA);
        unpack8(vueB, fueB); unpack8(vpvB, fpvB);
        float w1a = __expf(ra.x + bf2f(ipk_row[r2A]));
        float w2a = __expf(ra.y);
        float w1b = hb ? __expf(rb.x + bf2f(ipk_row[r2B])) : 0.f;
        float w2b = hb ? __expf(rb.y) : 0.f;
        s1 += w1a + w1b; s2 += w2a + w2b;
#pragma unroll
        for (int j = 0; j < 8; j++) {
            b1[j]  = fmaf(w1a, fueA[j], fmaf(w1b, fueB[j], b1[j]));
            bpv[j] = fmaf(w1a, fpvA[j], fmaf(w1b, fpvB[j], bpv[j]));
            b2[j]  = fmaf(w2a, fueA[j], fmaf(w2b, fueB[j], b2[j]));
        }
    }
#pragma unroll
    for (int d = 16; d < 64; d <<= 1) {
        s1 += __shfl_xor(s1, d); s2 += __shfl_xor(s2, d);
#pragma unroll
        for (int j = 0; j < 8; j++) {
            b1[j]  += __shfl_xor(b1[j], d);
            bpv[j] += __shfl_xor(bpv[j], d);
            b2[j]  += __shfl_xor(b2[j], d);
        }
    }
    if (lane < 16) {
        float inv1 = 1.f / s1, inv2 = 1.f / s2;
        *(bf16x8*)(B1n + (size_t)it * D_ + l16 * 8) = pack8(b1, inv1);
        *(bf16x8*)(PVn + (size_t)it * D_ + l16 * 8) = pack8(bpv, inv1);
        *(bf16x8*)(B2n + (size_t)it * D_ + l16 * 8) = pack8(b2, inv2);
    }
}

// ---------------- finish GEMM (4 configs via blockIdx.y), swapped-operand direct-store epilogue ----------------
struct FinArgs { const __bf16* A; const __bf16* W; const __bf16* side; const int* offseg; float* out; int rows; };
struct Fin4 { FinArgs f[4]; };
__global__ __launch_bounds__(256) void finish4(Fin4 fa) {
    FinArgs q = fa.f[blockIdx.y];
    if (blockIdx.x * 256 >= (unsigned)q.rows) return;
    __shared__ __bf16 sW[128][136];
    int t = threadIdx.x;
#pragma unroll
    for (int it = 0; it < 8; it++) {
        int slot = it * 256 + t;
        int r = slot >> 4, c16 = (slot & 15) * 8;
        bf16x8 v = *(const bf16x8*)(q.W + (size_t)r * D_ + c16);
        *(bf16x8*)(&sW[r][c16]) = v;
    }
    __syncthreads();
    int lane = t & 63, wave = t >> 6;
    int l16 = lane & 15, kh = lane >> 4;

    for (int tt = 0; tt < 4; tt++) {
        int rowblk = blockIdx.x * 256 + (tt * 4 + wave) * 16;
        if (rowblk >= q.rows) break;
        int ar = rowblk + l16;
        bool rok = ar < q.rows;
        int arc = rok ? ar : q.rows - 1;
        const __bf16* rA = q.A + (size_t)arc * D_;
        bf16x8 b0 = *(const bf16x8*)(rA + kh * 8);
        bf16x8 b1 = *(const bf16x8*)(rA + 32 + kh * 8);
        bf16x8 b2 = *(const bf16x8*)(rA + 64 + kh * 8);
        bf16x8 b3 = *(const bf16x8*)(rA + 96 + kh * 8);
        float addv = 0.f;
        if (!q.side && rok) addv = (q.offseg[ar + 1] - q.offseg[ar]) > 0 ? 1.f : 0.f;
#pragma unroll
        for (int cc = 0; cc < 8; cc++) {
            int wr = cc * 16 + l16;
            f32x4 acc = {};
            acc = __builtin_amdgcn_mfma_f32_16x16x32_bf16(*(const bf16x8*)(&sW[wr][kh * 8]), b0, acc, 0, 0, 0);
            acc = __builtin_amdgcn_mfma_f32_16x16x32_bf16(*(const bf16x8*)(&sW[wr][32 + kh * 8]), b1, acc, 0, 0, 0);
            acc = __builtin_amdgcn_mfma_f32_16x16x32_bf16(*(const bf16x8*)(&sW[wr][64 + kh * 8]), b2, acc, 0, 0, 0);
            acc = __builtin_amdgcn_mfma_f32_16x16x32_bf16(*(const bf16x8*)(&sW[wr][96 + kh * 8]), b3, acc, 0, 0, 0);
            if (rok) {
                int col = cc * 16 + kh * 4;
                float4 v = make_float4(acc[0], acc[1], acc[2], acc[3]);
                if (q.side) {
                    ushort4 sv = *(const ushort4*)((const unsigned short*)q.side + (size_t)ar * D_ + col);
                    v.x += __uint_as_float((uint32_t)sv.x << 16);
                    v.y += __uint_as_float((uint32_t)sv.y << 16);
                    v.z += __uint_as_float((uint32_t)sv.z << 16);
                    v.w += __uint_as_float((uint32_t)sv.w << 16);
                } else {
                    v.x += addv; v.y += addv; v.z += addv; v.w += addv;
                }
                *(float4*)(q.out + (size_t)ar * D_ + col) = v;
            }
        }
    }
}

extern "C" void kernel_launch(void* const* d_in, const int* in_sizes, int n_in,
                              void* d_out, int out_size, void* d_ws, size_t ws_size,
                              hipStream_t stream) {
    (void)n_in; (void)out_size; (void)ws_size;
    const float* u_emb = (const float*)d_in[0];
    const float* i_emb = (const float*)d_in[1];
    const int* edge_u = (const int*)d_in[2];
    const int* edge_i = (const int*)d_in[3];
    const int* rui = (const int*)d_in[4];
    const int* riu = (const int*)d_in[5];
    const int* last_u_items = (const int*)d_in[6];
    const int* last_i_users = (const int*)d_in[7];
    const float* W1  = (const float*)d_in[8];
    const float* W2  = (const float*)d_in[9];
    const float* W1b = (const float*)d_in[10];
    const float* W2b = (const float*)d_in[11];
    const float* W3  = (const float*)d_in[12];
    const float* W4  = (const float*)d_in[13];
    const float* pV  = (const float*)d_in[14];
    const float* pK  = (const float*)d_in[15];
    const float* last_user_table = (const float*)d_in[16];
    const float* last_item_table = (const float*)d_in[17];

    const int NU = in_sizes[0] / D_;
    const int NI = in_sizes[1] / D_;
    const int E  = in_sizes[2];
    const int UMAXr = in_sizes[14] / D_;
    const int IMAXr = in_sizes[15] / D_;
    const int NSEG = NU + NI;

    size_t cur = 0;
    auto alloc = [&](size_t bytes) -> void* {
        void* p = (char*)d_ws + cur;
        cur += (bytes + 255) & ~(size_t)255;
        return p;
    };

    __bf16* Wb4   = (__bf16*)alloc(4 * 16384 * 2);
    __bf16* M2t   = (__bf16*)alloc(16384 * 2);
    __bf16* M3t   = (__bf16*)alloc(16384 * 2);
    __bf16* M4t   = (__bf16*)alloc(16384 * 2);
    __bf16* pVW2  = (__bf16*)alloc((size_t)UMAXr * D_ * 2);
    __bf16* pKW1  = (__bf16*)alloc((size_t)IMAXr * D_ * 2);
    __bf16* pVb   = (__bf16*)alloc((size_t)UMAXr * D_ * 2);
    __bf16* pKb   = (__bf16*)alloc((size_t)IMAXr * D_ * 2);
    __bf16* ub_emb = (__bf16*)alloc((size_t)NU * D_ * 2);
    __bf16* ib_emb = (__bf16*)alloc((size_t)NI * D_ * 2);
    __bf16* um_t  = (__bf16*)alloc((size_t)NU * D_ * 2);
    __bf16* li_t  = (__bf16*)alloc((size_t)NU * D_ * 2);
    __bf16* lu_t  = (__bf16*)alloc((size_t)NU * D_ * 2);
    __bf16* upv   = (__bf16*)alloc((size_t)NU * UMAXr * 2);
    __bf16* ipk   = (__bf16*)alloc((size_t)NI * IMAXr * 2);
    __bf16* A1n   = (__bf16*)alloc((size_t)NU * D_ * 2);
    __bf16* PKn   = (__bf16*)alloc((size_t)NU * D_ * 2);
    __bf16* A2n   = (__bf16*)alloc((size_t)NU * D_ * 2);
    __bf16* B1n   = (__bf16*)alloc((size_t)NI * D_ * 2);
    __bf16* PVn   = (__bf16*)alloc((size_t)NI * D_ * 2);
    __bf16* B2n   = (__bf16*)alloc((size_t)NI * D_ * 2);
    float* mb_rec = (float*)alloc((size_t)E * 16);
    int* u_list   = (int*)alloc((size_t)E * 8);
    int* cnt_all  = (int*)alloc((size_t)NSEG * 4);
    int* off_all  = (int*)alloc((size_t)(NSEG + 1) * 4);
    int* pos_all  = (int*)alloc((size_t)NSEG * 4);
    int* parts    = (int*)alloc(1024 * 4);

    float* out = (float*)d_out;
    float* hLu = out;
    float* hSu = out + (size_t)NU * D_;
    float* hLi = out + (size_t)2 * NU * D_;
    float* hSi = out + (size_t)2 * NU * D_ + (size_t)NI * D_;

    // zero counters first (hist merged into prep_all)
    hipMemsetAsync(cnt_all, 0, (size_t)NSEG * 4, stream);

    // merged prep: weight/p casts + emb casts + histogram
    int npv = UMAXr * D_, npk = IMAXr * D_;
    size_t nue = (size_t)NU * D_, nie = (size_t)NI * D_;
    PrepArgs pa;
    pa.w.p[0] = W1; pa.w.p[1] = W2; pa.w.p[2] = W1b; pa.w.p[3] = W2b;
    pa.pV = pV; pa.pK = pK; pa.outW = Wb4; pa.pVb = pVb; pa.pKb = pKb; pa.npv = npv; pa.npk = npk;
    pa.u_emb = u_emb; pa.i_emb = i_emb; pa.ub = ub_emb; pa.ib = ib_emb; pa.nue = nue; pa.nie = nie;
    pa.eu = edge_u; pa.ei = edge_i; pa.cnt_all = cnt_all; pa.nu = NU; pa.E = E;
    pa.wb_blocks = (4 * 16384 + npv + npk + 255) / 256;
    pa.eb_blocks = (int)(((nue + nie) / 4 + 255) / 256);
    int hb_blocks = (E + 255) / 256;
    prep_all<<<pa.wb_blocks + pa.eb_blocks + hb_blocks, 256, 0, stream>>>(pa);

    prep_mats<<<128 + (UMAXr > IMAXr ? UMAXr : IMAXr), 128, 0, stream>>>(W1, W2, W3, W4, pV, pK,
                                                                         M2t, M3t, M4t, pVW2, pKW1, UMAXr, IMAXr);

    // CSR scan chain
    int nb = (NSEG + SCAN_TILE - 1) / SCAN_TILE;
    scan_phaseA<<<nb, 256, 0, stream>>>(cnt_all, parts, NSEG);
    scan_phaseB<<<1, 1024, 0, stream>>>(parts, nb, off_all, NSEG);
    scan_phaseC<<<nb, 256, 0, stream>>>(cnt_all, parts, off_all, pos_all, NSEG);
    scatter2<<<(E + 255) / 256, 256, 0, stream>>>(edge_u, edge_i, rui, riu, pos_all, u_list, NU, E);

    // merged: user vectors + pvk GEMMs (one launch)
    int gu = (NU + 63) / 64, gi = (NI + 63) / 64;
    int gmax = gu > gi ? gu : gi;
    VecsPvk vp;
    vp.u_emb = u_emb; vp.lit_tab = last_item_table; vp.g_li = last_u_items;
    vp.lut_tab = last_user_table; vp.g_lu = last_i_users;
    vp.M2t = M2t; vp.M3t = M3t; vp.M4t = M4t;
    vp.um_t = um_t; vp.li_t = li_t; vp.lu_t = lu_t; vp.nu = NU;
    vp.a[0] = {ub_emb, pVW2, upv, NU, UMAXr};
    vp.a[1] = {ib_emb, pKW1, ipk, NI, IMAXr};
    vecs_pvk<<<dim3(gmax, 3), 256, 0, stream>>>(vp);

    // edge passes
    user_pass<<<(NU + 3) / 4, 256, 0, stream>>>(off_all, u_list, ib_emb, um_t, li_t, lu_t,
                                                pKb, upv, mb_rec, A1n, PKn, A2n, NU, UMAXr);
    item_pass<<<(NI + 3) / 4, 256, 0, stream>>>(off_all, ub_emb, pVb, ipk, (const float4*)mb_rec,
                                                B1n, PVn, B2n, NU, NI, IMAXr, E);

    // finish projections (one launch, 4 configs)
    int fu = (NU + 255) / 256, fi = (NI + 255) / 256;
    Fin4 fa;
    fa.f[0] = {A1n, Wb4 + 2 * 16384, PKn, nullptr, hLu, NU};
    fa.f[1] = {A2n, Wb4 + 0 * 16384, nullptr, off_all, hSu, NU};
    fa.f[2] = {B1n, Wb4 + 3 * 16384, PVn, nullptr, hLi, NI};
    fa.f[3] = {B2n, Wb4 + 1 * 16384, nullptr, off_all + NU, hSi, NI};
    finish4<<<dim3((fu > fi ? fu : fi), 4), 256, 0, stream>>>(fa);
}